// Round 8
// baseline (333.075 us; speedup 1.0000x reference)
//
#include <hip/hip_runtime.h>
#include <hip/hip_bf16.h>
#include <cstdint>

// bf16 fragments as 8 x short (4 VGPRs) per cdna_hip_programming.md §3
typedef __attribute__((ext_vector_type(8))) short bf16x8;
typedef __attribute__((ext_vector_type(4))) float f32x4;
typedef __attribute__((ext_vector_type(16))) float f32x16;
typedef __attribute__((ext_vector_type(4))) uint16_t u16x4;

__device__ __forceinline__ uint16_t f2b(float f) {
  union { float f; uint32_t i; } v; v.f = f;
  return (uint16_t)((v.i + 0x7FFFu + ((v.i >> 16) & 1u)) >> 16);  // RNE
}

__device__ __forceinline__ uint32_t pkbf(float a, float b) {
  union { __hip_bfloat162 h2; uint32_t u; } c;
  c.h2 = __float22bfloat162_rn(make_float2(a, b));
  return c.u;   // low16 = a, high16 = b
}

// async global->LDS, 16B per lane; LDS dest is wave-uniform base + lane*16
#define GLDS16(g, l) __builtin_amdgcn_global_load_lds( \
    (const __attribute__((address_space(1))) void*)(g), \
    (__attribute__((address_space(3))) void*)(l), 16, 0, 0)

// ---------------------------------------------------------------------------
// fp32 -> bf16 convert (RNE) for all three inputs in one launch
// ---------------------------------------------------------------------------
__global__ __launch_bounds__(256) void cvt_all(
    const float* __restrict__ x, const float* __restrict__ wa, const float* __restrict__ wp,
    uint16_t* __restrict__ xb, uint16_t* __restrict__ wab, uint16_t* __restrict__ wpb) {
  const int i = (blockIdx.x * 256 + threadIdx.x) * 4;
  const float* src; uint16_t* dst; int off;
  if (i < 4194304)      { src = x;  dst = xb;  off = i; }
  else if (i < 7340032) { src = wa; dst = wab; off = i - 4194304; }
  else                  { src = wp; dst = wpb; off = i - 7340032; }
  const float4 v = *(const float4*)(src + off);
  u16x4 o;
  o.x = f2b(v.x); o.y = f2b(v.y); o.z = f2b(v.z); o.w = f2b(v.w);
  *(u16x4*)(dst + off) = o;
}

// ---------------------------------------------------------------------------
// C[M,N] = A[M,K] @ B[N,K]^T + bias[N]. A,B bf16, bias fp32, fp32 accumulate.
// ---------------------------------------------------------------------------
template <int BM, bool OUT_BF16>
__global__ __launch_bounds__(256) void gemm_bt_bias(
    const uint16_t* __restrict__ A, const uint16_t* __restrict__ B,
    const float* __restrict__ bias, void* __restrict__ Cv,
    int M, int N, int K) {
  constexpr int MI = BM / 32;            // acc rows of 16
  constexpr int CA = BM / 16;            // A chunks per k-half
  constexpr int CPW = (2 * (CA + 8)) / 4;
  constexpr int CT_PITCH = OUT_BF16 ? 72 : 68;
  constexpr size_t CT_BYTES = (size_t)4 * (BM / 2) * CT_PITCH * (OUT_BF16 ? 2 : 4);
  constexpr size_t ST_BYTES = (size_t)(2 * (BM * 32 + 4096)) * 2;
  constexpr size_t LB = CT_BYTES > ST_BYTES ? CT_BYTES : ST_BYTES;
  __shared__ alignas(16) unsigned char ldsb[LB];
  uint16_t* lds = (uint16_t*)ldsb;
  const int offB0 = BM * 32;             // u16 offsets
  const int offA1 = BM * 32 + 4096;
  const int offB1 = 2 * BM * 32 + 4096;

  const int tid = threadIdx.x;
  const int wave = tid >> 6, lane = tid & 63;
  const int q4 = lane >> 4, l16 = lane & 15;
  const int wm = wave >> 1, wn = wave & 1;
  const long blockM = (long)blockIdx.y * BM;
  const long blockN = (long)blockIdx.x * 128;

  f32x4 acc[MI][4] = {};

  for (int k0 = 0; k0 < K; k0 += 64) {
#pragma unroll
    for (int c = 0; c < CPW; ++c) {
      const int id = c * 4 + wave;       // wave-uniform
      const uint16_t* mat; long rowBase; int a, kk, off;
      if (id < CA)               { mat = A; rowBase = blockM; a = id;            kk = k0;      off = 0; }
      else if (id < CA + 8)      { mat = B; rowBase = blockN; a = id - CA;       kk = k0;      off = offB0; }
      else if (id < 2 * CA + 8)  { mat = A; rowBase = blockM; a = id - CA - 8;   kk = k0 + 32; off = offA1; }
      else                       { mat = B; rowBase = blockN; a = id - 2*CA - 8; kk = k0 + 32; off = offB1; }
      const int flat = a * 64 + lane;
      const int row = flat >> 2, seg = flat & 3;
      GLDS16(mat + (rowBase + row) * (long)K + kk + seg * 8, lds + off + a * 512);
    }
    __syncthreads();
#pragma unroll
    for (int h = 0; h < 2; ++h) {
      const uint16_t* Ah = lds + (h ? offA1 : 0);
      const uint16_t* Bh = lds + (h ? offB1 : offB0);
      bf16x8 af[MI], bfr[4];
#pragma unroll
      for (int i = 0; i < MI; ++i)
        af[i] = *(const bf16x8*)&Ah[(wm * (BM / 2) + i * 16 + l16) * 32 + q4 * 8];
#pragma unroll
      for (int j = 0; j < 4; ++j)
        bfr[j] = *(const bf16x8*)&Bh[(wn * 64 + j * 16 + l16) * 32 + q4 * 8];
#pragma unroll
      for (int i = 0; i < MI; ++i)
#pragma unroll
        for (int j = 0; j < 4; ++j)
          acc[i][j] = __builtin_amdgcn_mfma_f32_16x16x32_bf16(af[i], bfr[j], acc[i][j], 0, 0, 0);
    }
    __syncthreads();
  }

  // epilogue: acc (C/D layout: col=l16, row=q4*4+r) -> per-wave LDS tile -> vector stores
  if (OUT_BF16) {
    uint16_t* ct = lds + wave * (BM / 2) * 72;
#pragma unroll
    for (int j = 0; j < 4; ++j) {
      const float bv = bias[blockN + wn * 64 + j * 16 + l16];
#pragma unroll
      for (int i = 0; i < MI; ++i)
#pragma unroll
        for (int r = 0; r < 4; ++r)
          ct[(i * 16 + q4 * 4 + r) * 72 + j * 16 + l16] = f2b(acc[i][j][r] + bv);
    }
    __syncthreads();
    uint16_t* Cb = (uint16_t*)Cv;
#pragma unroll
    for (int st = 0; st < BM / 16; ++st) {
      const int flat = st * 64 + lane;
      const int row = flat >> 3, seg = flat & 7;
      const bf16x8 v = *(const bf16x8*)&ct[row * 72 + seg * 8];
      *(bf16x8*)&Cb[(blockM + wm * (BM / 2) + row) * (long)N + blockN + wn * 64 + seg * 8] = v;
    }
  } else {
    float* ct = (float*)ldsb + wave * (BM / 2) * 68;
#pragma unroll
    for (int j = 0; j < 4; ++j) {
      const float bv = bias[blockN + wn * 64 + j * 16 + l16];
#pragma unroll
      for (int i = 0; i < MI; ++i)
#pragma unroll
        for (int r = 0; r < 4; ++r)
          ct[(i * 16 + q4 * 4 + r) * 68 + j * 16 + l16] = acc[i][j][r] + bv;
    }
    __syncthreads();
    float* Cb = (float*)Cv;
#pragma unroll
    for (int st = 0; st < BM / 8; ++st) {
      const int flat = st * 64 + lane;
      const int row = flat >> 4, seg = flat & 15;
      const f32x4 v = *(const f32x4*)&ct[row * 68 + seg * 4];
      *(f32x4*)&Cb[(blockM + wm * (BM / 2) + row) * (long)N + blockN + wn * 64 + seg * 4] = v;
    }
  }
}

// ---------------------------------------------------------------------------
// Flash-style causal attention, S^T formulation, 32x32x16 MFMA.
// FUSED-PAIR blocks: 512 threads (8 waves) handle strip pair (31-p, p)
// sequentially; key tile = 256, wave w owns keys w*32..+31 (the per-wave
// body is identical to round 7). nkt(qb) = ceil((qb+1)/4); every pair sums
// to EXACTLY 9 tiles -> all 512 blocks identical work, no tail; 2 blocks/CU
// (LDS 69KB x2 = 138 <= 160KB), 16 waves/CU constant.
// Per-strip in-block merge of the 8 per-wave (m,l,O) partials via LDS.
// bh in LOW bits: XCD serves 4 of 32 heads -> K/V fits private L2.
// NaN guard: pm floored at -3e4 (round-7 lesson: all-masked tile otherwise
// sets m_i to ROUNDED -1e30*sc and exp2f(fmaf residual) = inf).
// ---------------------------------------------------------------------------
__global__ __launch_bounds__(512, 4) void attn_flash(
    const uint16_t* __restrict__ kqv, uint16_t* __restrict__ attn) {
  constexpr int T = 2048, C = 1024, C3 = 3072;
  __shared__ alignas(16) unsigned char ldsb[70656];
  uint16_t* KP = (uint16_t*)ldsb;             // [256][72] u16 (tile phase)
  uint16_t* Vt = (uint16_t*)(ldsb + 36864);   // [64][264] u16, rot-16 swizzle
  uint32_t* VtW = (uint32_t*)(ldsb + 36864);  // pitch 132 dwords
  float* mlb  = (float*)ldsb;                 // [8][2][32] (merge overlay)
  float* obuf = (float*)(ldsb + 2048);        // [8][32][66] f32 (merge overlay)

  const int tid = threadIdx.x;
  const int wave = tid >> 6, lane = tid & 63;
  const int l32 = lane & 31, hh = lane >> 5;
  const int pairi = blockIdx.x >> 5, bh = blockIdx.x & 31;
  const int b = bh >> 4, h = bh & 15;
  const size_t base = (size_t)b * T * C3;
  const int hD = h * 64;
  const int tr = tid >> 3, kch = tid & 7;   // tr 0..63
  const float sc = 0.125f * 1.4426950408889634f;  // D^-0.5 * log2(e)

  for (int ss = 0; ss < 2; ++ss) {
    const int qb = ss ? pairi : 31 - pairi;   // big strip first
    const int nkt = (qb + 4) >> 2;            // ceil((qb+1)/4) 256-key tiles
    const int qmax = qb * 64 + 63;

    // Q regs: qf[qc][m] = Q[qb*64+qc*32+l32][m*16 + hh*8 .. +7]
    bf16x8 qf[2][4];
#pragma unroll
    for (int qc = 0; qc < 2; ++qc)
#pragma unroll
      for (int m = 0; m < 4; ++m)
        qf[qc][m] = *(const bf16x8*)&kqv[base + (size_t)(qb * 64 + qc * 32 + l32) * C3 + C + hD + m * 16 + hh * 8];

    f32x16 o[2][2] = {};   // [qc][db]: O[q=qc*32+(r&3)+8*(r>>2)+4*hh][d=db*32+l32]
    float m_i[2] = {-1e30f, -1e30f}, l_i[2] = {0.f, 0.f};

    // prefetch tile 0 into VGPRs (K rows rr*64+tr; V key-pairs s2*64+tr)
    bf16x8 pk[4], pv0[2], pv1[2];
#pragma unroll
    for (int rr = 0; rr < 4; ++rr)
      pk[rr] = *(const bf16x8*)&kqv[base + (size_t)(rr * 64 + tr) * C3 + hD + kch * 8];
#pragma unroll
    for (int s2 = 0; s2 < 2; ++s2) {
      const size_t gg = base + (size_t)(2 * (s2 * 64 + tr)) * C3 + 2 * C + hD + kch * 8;
      pv0[s2] = *(const bf16x8*)&kqv[gg];
      pv1[s2] = *(const bf16x8*)&kqv[gg + C3];
    }

    for (int kt = 0; kt < nkt; ++kt) {
      __syncthreads();   // S1: prior tile's KP/Vt reads (or merge reads) done
      // stage K from prefetch regs (b128, LDS addr loop-invariant)
#pragma unroll
      for (int rr = 0; rr < 4; ++rr)
        *(bf16x8*)&KP[(rr * 64 + tr) * 72 + kch * 8] = pk[rr];
      // stage V transposed: v_perm pack key-pairs, rot-16 swizzle
#pragma unroll
      for (int s2 = 0; s2 < 2; ++s2) {
        const int colw = ((s2 * 64 + tr) + 8 * kch) & 127;
        const uint32_t* a0 = (const uint32_t*)&pv0[s2];
        const uint32_t* a1 = (const uint32_t*)&pv1[s2];
#pragma unroll
        for (int i = 0; i < 8; ++i) {
          const uint32_t w = (i & 1)
              ? __builtin_amdgcn_perm(a1[i >> 1], a0[i >> 1], 0x07060302u)
              : __builtin_amdgcn_perm(a1[i >> 1], a0[i >> 1], 0x05040100u);
          VtW[(kch * 8 + i) * 132 + colw] = w;
        }
      }
      __syncthreads();   // S2: staging visible
      // prefetch next tile (loads stay in flight across the compute phase)
      if (kt + 1 < nkt) {
        const int kb2 = (kt + 1) * 256;
#pragma unroll
        for (int rr = 0; rr < 4; ++rr)
          pk[rr] = *(const bf16x8*)&kqv[base + (size_t)(kb2 + rr * 64 + tr) * C3 + hD + kch * 8];
#pragma unroll
        for (int s2 = 0; s2 < 2; ++s2) {
          const size_t gg = base + (size_t)(kb2 + 2 * (s2 * 64 + tr)) * C3 + 2 * C + hD + kch * 8;
          pv0[s2] = *(const bf16x8*)&kqv[gg];
          pv1[s2] = *(const bf16x8*)&kqv[gg + C3];
        }
      }

      // wave w handles keys kt*256 + w*32 .. +31; skip if fully beyond strip
      const bool act = (kt * 256 + wave * 32) <= qmax;  // wave-uniform
      if (act) {
        bf16x8 kf[4];
#pragma unroll
        for (int m = 0; m < 4; ++m)
          kf[m] = *(const bf16x8*)&KP[(wave * 32 + l32) * 72 + m * 16 + hh * 8];

#pragma unroll
        for (int qc = 0; qc < 2; ++qc) {
          // S^T = K·Q^T : 32 keys x 32 q; lane holds S^T[key(r,hh)][q=l32]
          f32x16 z = {};
#pragma unroll
          for (int m = 0; m < 4; ++m)
            z = __builtin_amdgcn_mfma_f32_32x32x16_bf16(kf[m], qf[qc][m], z, 0, 0, 0);
          if (kt == nkt - 1) {   // diagonal tile: elementwise causal mask
            const int key0 = kt * 256 + wave * 32;
            const int qg = qb * 64 + qc * 32 + l32;
#pragma unroll
            for (int r = 0; r < 16; ++r) {
              const int kg = key0 + (r & 3) + 8 * (r >> 2) + 4 * hh;
              if (kg > qg) z[r] = -1e30f;
            }
          }
          // online softmax over this wave's 32 keys (hh-pair exchange only)
          float mloc = -1e30f;
#pragma unroll
          for (int r = 0; r < 16; ++r) mloc = fmaxf(mloc, z[r]);
          mloc = fmaxf(mloc, __shfl_xor(mloc, 32, 64));
          const float pm = fmaxf(mloc * sc, -3.0e4f);   // NaN-guard floor
          if (__any(pm - m_i[qc] > 8.0f)) {   // defer-max
            const float mnew = fmaxf(m_i[qc], pm);
            const float alpha = exp2f(m_i[qc] - mnew);
#pragma unroll
            for (int r = 0; r < 16; ++r) {
              const float ar = __shfl(alpha, (r & 3) + 8 * (r >> 2) + 4 * hh, 64);
              o[qc][0][r] *= ar;
              o[qc][1][r] *= ar;
            }
            l_i[qc] *= alpha;
            m_i[qc] = mnew;
          }
          float rs = 0.f;
#pragma unroll
          for (int r = 0; r < 16; ++r) {
            const float pe = exp2f(fmaf(z[r], sc, -m_i[qc]));
            z[r] = pe;
            rs += pe;
          }
          rs += __shfl_xor(rs, 32, 64);
          l_i[qc] += rs;

          // O += P·V : pack P to bf16, lane-half exchange, 2 k-chunks
          uint32_t x0 = pkbf(z[0], z[1]),   x1 = pkbf(z[2], z[3]);
          uint32_t y0 = pkbf(z[4], z[5]),   y1 = pkbf(z[6], z[7]);
          uint32_t x2 = pkbf(z[8], z[9]),   x3 = pkbf(z[10], z[11]);
          uint32_t y2 = pkbf(z[12], z[13]), y3 = pkbf(z[14], z[15]);
          const uint32_t s0 = hh ? x0 : y0, s1 = hh ? x1 : y1;
          const uint32_t s2 = hh ? x2 : y2, s3 = hh ? x3 : y3;
          const uint32_t t0 = __shfl_xor(s0, 32, 64), t1 = __shfl_xor(s1, 32, 64);
          const uint32_t t2 = __shfl_xor(s2, 32, 64), t3 = __shfl_xor(s3, 32, 64);
#pragma unroll
          for (int cc = 0; cc < 2; ++cc) {
            union { bf16x8 v; uint32_t w[4]; } pa;
            if (cc == 0) {
              pa.w[0] = hh ? t0 : x0; pa.w[1] = hh ? t1 : x1;   // keys 8hh+0..3
              pa.w[2] = hh ? y0 : t0; pa.w[3] = hh ? y1 : t1;   // keys 8hh+4..7
            } else {
              pa.w[0] = hh ? t2 : x2; pa.w[1] = hh ? t3 : x3;
              pa.w[2] = hh ? y2 : t2; pa.w[3] = hh ? y3 : t3;
            }
#pragma unroll
            for (int db = 0; db < 2; ++db) {
              const int d = db * 32 + l32;
              const int col = (wave * 32 + cc * 16 + hh * 8 + 16 * (d >> 3)) & 255;
              const bf16x8 vf = *(const bf16x8*)&Vt[d * 264 + col];
              o[qc][db] = __builtin_amdgcn_mfma_f32_32x32x16_bf16(pa.v, vf, o[qc][db], 0, 0, 0);
            }
          }
        }
      }
    }

    // ---- in-block merge of 8 per-wave partials, one qc-half at a time ----
#pragma unroll
    for (int qc = 0; qc < 2; ++qc) {
      __syncthreads();   // tiles done (qc=0) / obuf reads done (qc=1)
      if (hh == 0) {
        mlb[wave * 64 + l32] = m_i[qc];
        mlb[wave * 64 + 32 + l32] = l_i[qc];
      }
#pragma unroll
      for (int r = 0; r < 16; ++r) {
        const int ql = (r & 3) + 8 * (r >> 2) + 4 * hh;
        const int bw = wave * 2112 + ql * 66 + l32;
        obuf[bw] = o[qc][0][r];
        obuf[bw + 32] = o[qc][1][r];
      }
      __syncthreads();
      // sum phase: thread = (row q = l32, col-block cb = wave*2+hh, 4 d each)
      float mw[8], lw[8];
#pragma unroll
      for (int w = 0; w < 8; ++w) {
        mw[w] = mlb[w * 64 + l32];
        lw[w] = mlb[w * 64 + 32 + l32];
      }
      float M = mw[0];
#pragma unroll
      for (int w = 1; w < 8; ++w) M = fmaxf(M, mw[w]);
      float L = 0.f, ww[8];
#pragma unroll
      for (int w = 0; w < 8; ++w) { ww[w] = exp2f(mw[w] - M); L += lw[w] * ww[w]; }
      const float Li = 1.0f / L;
      const int cb = wave * 2 + hh;   // 0..15, 4 d-columns each
      float acc[4] = {};
#pragma unroll
      for (int w = 0; w < 8; ++w) {
        const float2 v0 = *(const float2*)&obuf[w * 2112 + l32 * 66 + cb * 4];
        const float2 v1 = *(const float2*)&obuf[w * 2112 + l32 * 66 + cb * 4 + 2];
        acc[0] += v0.x * ww[w]; acc[1] += v0.y * ww[w];
        acc[2] += v1.x * ww[w]; acc[3] += v1.y * ww[w];
      }
      union { u16x4 v; uint32_t w2[2]; } ov;
      ov.w2[0] = pkbf(acc[0] * Li, acc[1] * Li);
      ov.w2[1] = pkbf(acc[2] * Li, acc[3] * Li);
      *(u16x4*)&attn[((size_t)b * T + qb * 64 + qc * 32 + l32) * C + hD + cb * 4] = ov.v;
    }
  }
}

extern "C" void kernel_launch(void* const* d_in, const int* in_sizes, int n_in,
                              void* d_out, int out_size, void* d_ws, size_t ws_size,
                              hipStream_t stream) {
  const float* x      = (const float*)d_in[0];  // (2,2048,1024) fp32
  const float* w_attn = (const float*)d_in[1];  // (3072,1024)  fp32
  const float* b_attn = (const float*)d_in[2];  // (3072,)      fp32
  const float* w_proj = (const float*)d_in[3];  // (1024,1024)  fp32
  const float* b_proj = (const float*)d_in[4];  // (1024,)      fp32
  float* out = (float*)d_out;                   // (2,2048,1024) fp32

  // ws layout (bf16): xb | wab | wpb | kqv | attnb
  uint16_t* xb    = (uint16_t*)d_ws;                     // 4096*1024
  uint16_t* wab   = xb  + (size_t)4096 * 1024;           // 3072*1024
  uint16_t* wpb   = wab + (size_t)3072 * 1024;           // 1024*1024
  uint16_t* kqv   = wpb + (size_t)1024 * 1024;           // 4096*3072
  uint16_t* attnb = kqv + (size_t)4096 * 3072;           // 4096*1024

  dim3 blk(256, 1, 1);
  hipLaunchKernelGGL(cvt_all, dim3(8192), blk, 0, stream, x, w_attn, w_proj, xb, wab, wpb);

  hipLaunchKernelGGL((gemm_bt_bias<128, true>), dim3(3072 / 128, 4096 / 128, 1), blk, 0, stream,
                     xb, wab, b_attn, (void*)kqv, 4096, 3072, 1024);
  hipLaunchKernelGGL(attn_flash, dim3(512, 1, 1), dim3(512, 1, 1), 0, stream, kqv, attnb);
  hipLaunchKernelGGL((gemm_bt_bias<64, false>), dim3(1024 / 128, 4096 / 64, 1), blk, 0, stream,
                     attnb, wpb, b_proj, (void*)out, 4096, 1024, 1024);
}

// Round 9
// 193.317 us; speedup vs baseline: 1.7229x; 1.7229x over previous
//
#include <hip/hip_runtime.h>
#include <hip/hip_bf16.h>
#include <cstdint>

// bf16 fragments as 8 x short (4 VGPRs) per cdna_hip_programming.md §3
typedef __attribute__((ext_vector_type(8))) short bf16x8;
typedef __attribute__((ext_vector_type(4))) float f32x4;
typedef __attribute__((ext_vector_type(16))) float f32x16;
typedef __attribute__((ext_vector_type(4))) uint16_t u16x4;

__device__ __forceinline__ uint16_t f2b(float f) {
  union { float f; uint32_t i; } v; v.f = f;
  return (uint16_t)((v.i + 0x7FFFu + ((v.i >> 16) & 1u)) >> 16);  // RNE
}

__device__ __forceinline__ uint32_t pkbf(float a, float b) {
  union { __hip_bfloat162 h2; uint32_t u; } c;
  c.h2 = __float22bfloat162_rn(make_float2(a, b));
  return c.u;   // low16 = a, high16 = b
}

// async global->LDS, 16B per lane; LDS dest is wave-uniform base + lane*16
#define GLDS16(g, l) __builtin_amdgcn_global_load_lds( \
    (const __attribute__((address_space(1))) void*)(g), \
    (__attribute__((address_space(3))) void*)(l), 16, 0, 0)

// ---------------------------------------------------------------------------
// fp32 -> bf16 convert (RNE) for all three inputs in one launch
// ---------------------------------------------------------------------------
__global__ __launch_bounds__(256) void cvt_all(
    const float* __restrict__ x, const float* __restrict__ wa, const float* __restrict__ wp,
    uint16_t* __restrict__ xb, uint16_t* __restrict__ wab, uint16_t* __restrict__ wpb) {
  const int i = (blockIdx.x * 256 + threadIdx.x) * 4;
  const float* src; uint16_t* dst; int off;
  if (i < 4194304)      { src = x;  dst = xb;  off = i; }
  else if (i < 7340032) { src = wa; dst = wab; off = i - 4194304; }
  else                  { src = wp; dst = wpb; off = i - 7340032; }
  const float4 v = *(const float4*)(src + off);
  u16x4 o;
  o.x = f2b(v.x); o.y = f2b(v.y); o.z = f2b(v.z); o.w = f2b(v.w);
  *(u16x4*)(dst + off) = o;
}

// ---------------------------------------------------------------------------
// C[M,N] = A[M,K] @ B[N,K]^T + bias[N]. A,B bf16, bias fp32, fp32 accumulate.
// ---------------------------------------------------------------------------
template <int BM, bool OUT_BF16>
__global__ __launch_bounds__(256) void gemm_bt_bias(
    const uint16_t* __restrict__ A, const uint16_t* __restrict__ B,
    const float* __restrict__ bias, void* __restrict__ Cv,
    int M, int N, int K) {
  constexpr int MI = BM / 32;            // acc rows of 16
  constexpr int CA = BM / 16;            // A chunks per k-half
  constexpr int CPW = (2 * (CA + 8)) / 4;
  constexpr int CT_PITCH = OUT_BF16 ? 72 : 68;
  constexpr size_t CT_BYTES = (size_t)4 * (BM / 2) * CT_PITCH * (OUT_BF16 ? 2 : 4);
  constexpr size_t ST_BYTES = (size_t)(2 * (BM * 32 + 4096)) * 2;
  constexpr size_t LB = CT_BYTES > ST_BYTES ? CT_BYTES : ST_BYTES;
  __shared__ alignas(16) unsigned char ldsb[LB];
  uint16_t* lds = (uint16_t*)ldsb;
  const int offB0 = BM * 32;             // u16 offsets
  const int offA1 = BM * 32 + 4096;
  const int offB1 = 2 * BM * 32 + 4096;

  const int tid = threadIdx.x;
  const int wave = tid >> 6, lane = tid & 63;
  const int q4 = lane >> 4, l16 = lane & 15;
  const int wm = wave >> 1, wn = wave & 1;
  const long blockM = (long)blockIdx.y * BM;
  const long blockN = (long)blockIdx.x * 128;

  f32x4 acc[MI][4] = {};

  for (int k0 = 0; k0 < K; k0 += 64) {
#pragma unroll
    for (int c = 0; c < CPW; ++c) {
      const int id = c * 4 + wave;       // wave-uniform
      const uint16_t* mat; long rowBase; int a, kk, off;
      if (id < CA)               { mat = A; rowBase = blockM; a = id;            kk = k0;      off = 0; }
      else if (id < CA + 8)      { mat = B; rowBase = blockN; a = id - CA;       kk = k0;      off = offB0; }
      else if (id < 2 * CA + 8)  { mat = A; rowBase = blockM; a = id - CA - 8;   kk = k0 + 32; off = offA1; }
      else                       { mat = B; rowBase = blockN; a = id - 2*CA - 8; kk = k0 + 32; off = offB1; }
      const int flat = a * 64 + lane;
      const int row = flat >> 2, seg = flat & 3;
      GLDS16(mat + (rowBase + row) * (long)K + kk + seg * 8, lds + off + a * 512);
    }
    __syncthreads();
#pragma unroll
    for (int h = 0; h < 2; ++h) {
      const uint16_t* Ah = lds + (h ? offA1 : 0);
      const uint16_t* Bh = lds + (h ? offB1 : offB0);
      bf16x8 af[MI], bfr[4];
#pragma unroll
      for (int i = 0; i < MI; ++i)
        af[i] = *(const bf16x8*)&Ah[(wm * (BM / 2) + i * 16 + l16) * 32 + q4 * 8];
#pragma unroll
      for (int j = 0; j < 4; ++j)
        bfr[j] = *(const bf16x8*)&Bh[(wn * 64 + j * 16 + l16) * 32 + q4 * 8];
#pragma unroll
      for (int i = 0; i < MI; ++i)
#pragma unroll
        for (int j = 0; j < 4; ++j)
          acc[i][j] = __builtin_amdgcn_mfma_f32_16x16x32_bf16(af[i], bfr[j], acc[i][j], 0, 0, 0);
    }
    __syncthreads();
  }

  // epilogue: acc (C/D layout: col=l16, row=q4*4+r) -> per-wave LDS tile -> vector stores
  if (OUT_BF16) {
    uint16_t* ct = lds + wave * (BM / 2) * 72;
#pragma unroll
    for (int j = 0; j < 4; ++j) {
      const float bv = bias[blockN + wn * 64 + j * 16 + l16];
#pragma unroll
      for (int i = 0; i < MI; ++i)
#pragma unroll
        for (int r = 0; r < 4; ++r)
          ct[(i * 16 + q4 * 4 + r) * 72 + j * 16 + l16] = f2b(acc[i][j][r] + bv);
    }
    __syncthreads();
    uint16_t* Cb = (uint16_t*)Cv;
#pragma unroll
    for (int st = 0; st < BM / 16; ++st) {
      const int flat = st * 64 + lane;
      const int row = flat >> 3, seg = flat & 7;
      const bf16x8 v = *(const bf16x8*)&ct[row * 72 + seg * 8];
      *(bf16x8*)&Cb[(blockM + wm * (BM / 2) + row) * (long)N + blockN + wn * 64 + seg * 8] = v;
    }
  } else {
    float* ct = (float*)ldsb + wave * (BM / 2) * 68;
#pragma unroll
    for (int j = 0; j < 4; ++j) {
      const float bv = bias[blockN + wn * 64 + j * 16 + l16];
#pragma unroll
      for (int i = 0; i < MI; ++i)
#pragma unroll
        for (int r = 0; r < 4; ++r)
          ct[(i * 16 + q4 * 4 + r) * 68 + j * 16 + l16] = acc[i][j][r] + bv;
    }
    __syncthreads();
    float* Cb = (float*)Cv;
#pragma unroll
    for (int st = 0; st < BM / 8; ++st) {
      const int flat = st * 64 + lane;
      const int row = flat >> 4, seg = flat & 15;
      const f32x4 v = *(const f32x4*)&ct[row * 68 + seg * 4];
      *(f32x4*)&Cb[(blockM + wm * (BM / 2) + row) * (long)N + blockN + wn * 64 + seg * 4] = v;
    }
  }
}

// ---------------------------------------------------------------------------
// Flash-style causal attention, S^T formulation, 32x32x16 MFMA,
// IN-BLOCK split-K (round-7 verified body): block = 64 q rows; each of 4
// waves handles keys w*32..w*32+31 of every 128-key tile across ALL 64 q,
// per-wave online softmax, in-block LDS merge per strip.
// PAIRED STRIPS (round-0 schedule): 512 blocks x 256 thr; block p processes
// strip (31-p) then (p) -> EXACTLY 17 tiles per block, zero tail, constant
// 2 blocks/CU = 8 waves/CU (r7's decaying-occupancy fix; r8's 512-thread
// fusion spilled: __launch_bounds__ 2nd arg is min BLOCKS/CU -> VGPR 64).
// bh in LOW bits: XCD serves 4 of 32 heads -> K/V fits private L2.
// NaN guard: pm floored at -3e4 (all-masked tile otherwise sets m_i to the
// ROUNDED -1e30*sc and exp2f(fmaf residual) = inf).
// ---------------------------------------------------------------------------
__global__ __launch_bounds__(256, 2) void attn_flash(
    const uint16_t* __restrict__ kqv, uint16_t* __restrict__ attn) {
  constexpr int T = 2048, C = 1024, C3 = 3072;
  __shared__ alignas(16) unsigned char ldsb[35840];
  uint16_t* KP = (uint16_t*)ldsb;             // [128][72] u16 (tile phase)
  uint16_t* Vt = (uint16_t*)(ldsb + 18432);   // [64][136] u16, rot-16 swizzle
  uint32_t* VtW = (uint32_t*)(ldsb + 18432);  // pitch 68 dwords
  float* mlb  = (float*)ldsb;                 // [4][2][32] (merge overlay)
  float* obuf = (float*)(ldsb + 1024);        // [4][32][66] f32 (merge overlay)

  const int tid = threadIdx.x;
  const int wave = tid >> 6, lane = tid & 63;
  const int l32 = lane & 31, hh = lane >> 5;
  const int pairi = blockIdx.x >> 5, bh = blockIdx.x & 31;
  const int b = bh >> 4, h = bh & 15;
  const size_t base = (size_t)b * T * C3;
  const int hD = h * 64;
  const int tr = tid >> 3, kch = tid & 7;
  const float sc = 0.125f * 1.4426950408889634f;  // D^-0.5 * log2(e)

  for (int ss = 0; ss < 2; ++ss) {
    const int qb = ss ? pairi : 31 - pairi;   // big strip first
    const int nkt = (qb >> 1) + 1;

    // Q regs: qf[qc][m], B-frag col=l32, k=hh*8+j
    bf16x8 qf[2][4];
#pragma unroll
    for (int qc = 0; qc < 2; ++qc)
#pragma unroll
      for (int m = 0; m < 4; ++m)
        qf[qc][m] = *(const bf16x8*)&kqv[base + (size_t)(qb * 64 + qc * 32 + l32) * C3 + C + hD + m * 16 + hh * 8];

    f32x16 o[2][2] = {};   // [qc][db]: O[q=qc*32+(r&3)+8*(r>>2)+4*hh][d=db*32+l32]
    float m_i[2] = {-1e30f, -1e30f}, l_i[2] = {0.f, 0.f};

    // prefetch tile 0 into VGPRs
    bf16x8 pk[4], pv0[2], pv1[2];
#pragma unroll
    for (int rr = 0; rr < 4; ++rr)
      pk[rr] = *(const bf16x8*)&kqv[base + (size_t)(rr * 32 + tr) * C3 + hD + kch * 8];
#pragma unroll
    for (int s2 = 0; s2 < 2; ++s2) {
      const size_t gg = base + (size_t)(2 * (s2 * 32 + tr)) * C3 + 2 * C + hD + kch * 8;
      pv0[s2] = *(const bf16x8*)&kqv[gg];
      pv1[s2] = *(const bf16x8*)&kqv[gg + C3];
    }

    for (int kt = 0; kt < nkt; ++kt) {
      __syncthreads();   // S1: prior tile's KP/Vt reads (or prior merge reads) done
      // stage K from prefetch regs (b128, LDS addr loop-invariant)
#pragma unroll
      for (int rr = 0; rr < 4; ++rr)
        *(bf16x8*)&KP[(rr * 32 + tr) * 72 + kch * 8] = pk[rr];
      // stage V transposed: v_perm pack key-pairs, rot-16 swizzle
#pragma unroll
      for (int s2 = 0; s2 < 2; ++s2) {
        const int colw = ((s2 * 32 + tr) + 8 * kch) & 63;
        const uint32_t* a0 = (const uint32_t*)&pv0[s2];
        const uint32_t* a1 = (const uint32_t*)&pv1[s2];
#pragma unroll
        for (int i = 0; i < 8; ++i) {
          const uint32_t w = (i & 1)
              ? __builtin_amdgcn_perm(a1[i >> 1], a0[i >> 1], 0x07060302u)
              : __builtin_amdgcn_perm(a1[i >> 1], a0[i >> 1], 0x05040100u);
          VtW[(kch * 8 + i) * 68 + colw] = w;
        }
      }
      __syncthreads();   // S2: staging visible
      // prefetch next tile (loads stay in flight across the compute phase)
      if (kt + 1 < nkt) {
        const int kb2 = (kt + 1) * 128;
#pragma unroll
        for (int rr = 0; rr < 4; ++rr)
          pk[rr] = *(const bf16x8*)&kqv[base + (size_t)(kb2 + rr * 32 + tr) * C3 + hD + kch * 8];
#pragma unroll
        for (int s2 = 0; s2 < 2; ++s2) {
          const size_t gg = base + (size_t)(kb2 + 2 * (s2 * 32 + tr)) * C3 + 2 * C + hD + kch * 8;
          pv0[s2] = *(const bf16x8*)&kqv[gg];
          pv1[s2] = *(const bf16x8*)&kqv[gg + C3];
        }
      }

      // wave w handles keys kt*128 + w*32 .. +31; skip if fully beyond strip
      const int key0 = kt * 128 + wave * 32;
      if (key0 <= qb * 64 + 63) {   // wave-uniform
        bf16x8 kf[4];
#pragma unroll
        for (int m = 0; m < 4; ++m)
          kf[m] = *(const bf16x8*)&KP[(wave * 32 + l32) * 72 + m * 16 + hh * 8];

#pragma unroll
        for (int qc = 0; qc < 2; ++qc) {
          // per-qc skip: slice fully masked for this q-half (diag tile only)
          if (key0 > qb * 64 + qc * 32 + 31) continue;   // wave-uniform
          // S^T = K·Q^T : 32 keys x 32 q; lane holds S^T[key(r,hh)][q=l32]
          f32x16 z = {};
#pragma unroll
          for (int m = 0; m < 4; ++m)
            z = __builtin_amdgcn_mfma_f32_32x32x16_bf16(kf[m], qf[qc][m], z, 0, 0, 0);
          if (kt == nkt - 1) {   // diagonal tile: elementwise causal mask
            const int qg = qb * 64 + qc * 32 + l32;
#pragma unroll
            for (int r = 0; r < 16; ++r) {
              const int kg = key0 + (r & 3) + 8 * (r >> 2) + 4 * hh;
              if (kg > qg) z[r] = -1e30f;
            }
          }
          // online softmax over this wave's 32 keys (hh-pair exchange only)
          float mloc = -1e30f;
#pragma unroll
          for (int r = 0; r < 16; ++r) mloc = fmaxf(mloc, z[r]);
          mloc = fmaxf(mloc, __shfl_xor(mloc, 32, 64));
          const float pm = fmaxf(mloc * sc, -3.0e4f);   // NaN-guard floor
          if (__any(pm - m_i[qc] > 8.0f)) {   // defer-max
            const float mnew = fmaxf(m_i[qc], pm);
            const float alpha = exp2f(m_i[qc] - mnew);
#pragma unroll
            for (int r = 0; r < 16; ++r) {
              const float ar = __shfl(alpha, (r & 3) + 8 * (r >> 2) + 4 * hh, 64);
              o[qc][0][r] *= ar;
              o[qc][1][r] *= ar;
            }
            l_i[qc] *= alpha;
            m_i[qc] = mnew;
          }
          float rs = 0.f;
#pragma unroll
          for (int r = 0; r < 16; ++r) {
            const float pe = exp2f(fmaf(z[r], sc, -m_i[qc]));
            z[r] = pe;
            rs += pe;
          }
          rs += __shfl_xor(rs, 32, 64);
          l_i[qc] += rs;

          // O += P·V : pack P to bf16, lane-half exchange, 2 k-chunks
          uint32_t x0 = pkbf(z[0], z[1]),   x1 = pkbf(z[2], z[3]);
          uint32_t y0 = pkbf(z[4], z[5]),   y1 = pkbf(z[6], z[7]);
          uint32_t x2 = pkbf(z[8], z[9]),   x3 = pkbf(z[10], z[11]);
          uint32_t y2 = pkbf(z[12], z[13]), y3 = pkbf(z[14], z[15]);
          const uint32_t s0 = hh ? x0 : y0, s1 = hh ? x1 : y1;
          const uint32_t s2 = hh ? x2 : y2, s3 = hh ? x3 : y3;
          const uint32_t t0 = __shfl_xor(s0, 32, 64), t1 = __shfl_xor(s1, 32, 64);
          const uint32_t t2 = __shfl_xor(s2, 32, 64), t3 = __shfl_xor(s3, 32, 64);
#pragma unroll
          for (int cc = 0; cc < 2; ++cc) {
            union { bf16x8 v; uint32_t w[4]; } pa;
            if (cc == 0) {
              pa.w[0] = hh ? t0 : x0; pa.w[1] = hh ? t1 : x1;   // keys 8hh+0..3
              pa.w[2] = hh ? y0 : t0; pa.w[3] = hh ? y1 : t1;   // keys 8hh+4..7
            } else {
              pa.w[0] = hh ? t2 : x2; pa.w[1] = hh ? t3 : x3;
              pa.w[2] = hh ? y2 : t2; pa.w[3] = hh ? y3 : t3;
            }
#pragma unroll
            for (int db = 0; db < 2; ++db) {
              const int d = db * 32 + l32;
              const int col = (wave * 32 + cc * 16 + hh * 8 + 16 * (d >> 3)) & 127;
              const bf16x8 vf = *(const bf16x8*)&Vt[d * 136 + col];
              o[qc][db] = __builtin_amdgcn_mfma_f32_32x32x16_bf16(pa.v, vf, o[qc][db], 0, 0, 0);
            }
          }
        }
      }
    }

    // ---- in-block merge of 4 per-wave partials, one qc-half at a time ----
#pragma unroll
    for (int qc = 0; qc < 2; ++qc) {
      __syncthreads();   // tiles done (qc=0) / obuf reads done (qc=1)
      if (hh == 0) {
        mlb[wave * 64 + l32] = m_i[qc];
        mlb[wave * 64 + 32 + l32] = l_i[qc];
      }
#pragma unroll
      for (int r = 0; r < 16; ++r) {
        const int ql = (r & 3) + 8 * (r >> 2) + 4 * hh;
        const int bw = wave * 2112 + ql * 66 + l32;
        obuf[bw] = o[qc][0][r];
        obuf[bw + 32] = o[qc][1][r];
      }
      __syncthreads();
      // sum phase: thread = (row q = l32, col-block cb = wave*2+hh)
      float mw[4], lw[4];
#pragma unroll
      for (int w = 0; w < 4; ++w) {
        mw[w] = mlb[w * 64 + l32];
        lw[w] = mlb[w * 64 + 32 + l32];
      }
      const float M = fmaxf(fmaxf(mw[0], mw[1]), fmaxf(mw[2], mw[3]));
      float L = 0.f, ww[4];
#pragma unroll
      for (int w = 0; w < 4; ++w) { ww[w] = exp2f(mw[w] - M); L += lw[w] * ww[w]; }
      const float Li = 1.0f / L;
      const int cb = wave * 2 + hh;
      float acc[8] = {};
#pragma unroll
      for (int w = 0; w < 4; ++w)
#pragma unroll
        for (int p = 0; p < 4; ++p) {
          const float2 v = *(const float2*)&obuf[w * 2112 + l32 * 66 + cb * 8 + p * 2];
          acc[2 * p]     += v.x * ww[w];
          acc[2 * p + 1] += v.y * ww[w];
        }
      union { bf16x8 v; uint32_t w4[4]; } ov;
#pragma unroll
      for (int p = 0; p < 4; ++p)
        ov.w4[p] = pkbf(acc[2 * p] * Li, acc[2 * p + 1] * Li);
      *(bf16x8*)&attn[((size_t)b * T + qb * 64 + qc * 32 + l32) * C + hD + cb * 8] = ov.v;
    }
  }
}

extern "C" void kernel_launch(void* const* d_in, const int* in_sizes, int n_in,
                              void* d_out, int out_size, void* d_ws, size_t ws_size,
                              hipStream_t stream) {
  const float* x      = (const float*)d_in[0];  // (2,2048,1024) fp32
  const float* w_attn = (const float*)d_in[1];  // (3072,1024)  fp32
  const float* b_attn = (const float*)d_in[2];  // (3072,)      fp32
  const float* w_proj = (const float*)d_in[3];  // (1024,1024)  fp32
  const float* b_proj = (const float*)d_in[4];  // (1024,)      fp32
  float* out = (float*)d_out;                   // (2,2048,1024) fp32

  // ws layout (bf16): xb | wab | wpb | kqv | attnb
  uint16_t* xb    = (uint16_t*)d_ws;                     // 4096*1024
  uint16_t* wab   = xb  + (size_t)4096 * 1024;           // 3072*1024
  uint16_t* wpb   = wab + (size_t)3072 * 1024;           // 1024*1024
  uint16_t* kqv   = wpb + (size_t)1024 * 1024;           // 4096*3072
  uint16_t* attnb = kqv + (size_t)4096 * 3072;           // 4096*1024

  dim3 blk(256, 1, 1);
  hipLaunchKernelGGL(cvt_all, dim3(8192), blk, 0, stream, x, w_attn, w_proj, xb, wab, wpb);

  hipLaunchKernelGGL((gemm_bt_bias<128, true>), dim3(3072 / 128, 4096 / 128, 1), blk, 0, stream,
                     xb, wab, b_attn, (void*)kqv, 4096, 3072, 1024);
  hipLaunchKernelGGL(attn_flash, dim3(512, 1, 1), blk, 0, stream, kqv, attnb);
  hipLaunchKernelGGL((gemm_bt_bias<64, false>), dim3(1024 / 128, 4096 / 64, 1), blk, 0, stream,
                     attnb, wpb, b_proj, (void*)out, 4096, 1024, 1024);
}

// Round 10
// 193.012 us; speedup vs baseline: 1.7257x; 1.0016x over previous
//
#include <hip/hip_runtime.h>
#include <hip/hip_bf16.h>
#include <cstdint>

// bf16 fragments as 8 x short (4 VGPRs) per cdna_hip_programming.md §3
typedef __attribute__((ext_vector_type(8))) short bf16x8;
typedef __attribute__((ext_vector_type(4))) float f32x4;
typedef __attribute__((ext_vector_type(16))) float f32x16;
typedef __attribute__((ext_vector_type(4))) uint16_t u16x4;

__device__ __forceinline__ uint16_t f2b(float f) {
  union { float f; uint32_t i; } v; v.f = f;
  return (uint16_t)((v.i + 0x7FFFu + ((v.i >> 16) & 1u)) >> 16);  // RNE
}

__device__ __forceinline__ uint32_t pkbf(float a, float b) {
  union { __hip_bfloat162 h2; uint32_t u; } c;
  c.h2 = __float22bfloat162_rn(make_float2(a, b));
  return c.u;   // low16 = a, high16 = b
}

// async global->LDS, 16B per lane; LDS dest is wave-uniform base + lane*16
#define GLDS16(g, l) __builtin_amdgcn_global_load_lds( \
    (const __attribute__((address_space(1))) void*)(g), \
    (__attribute__((address_space(3))) void*)(l), 16, 0, 0)

// ---------------------------------------------------------------------------
// fp32 -> bf16 convert (RNE) for all three inputs in one launch
// ---------------------------------------------------------------------------
__global__ __launch_bounds__(256) void cvt_all(
    const float* __restrict__ x, const float* __restrict__ wa, const float* __restrict__ wp,
    uint16_t* __restrict__ xb, uint16_t* __restrict__ wab, uint16_t* __restrict__ wpb) {
  const int i = (blockIdx.x * 256 + threadIdx.x) * 4;
  const float* src; uint16_t* dst; int off;
  if (i < 4194304)      { src = x;  dst = xb;  off = i; }
  else if (i < 7340032) { src = wa; dst = wab; off = i - 4194304; }
  else                  { src = wp; dst = wpb; off = i - 7340032; }
  const float4 v = *(const float4*)(src + off);
  u16x4 o;
  o.x = f2b(v.x); o.y = f2b(v.y); o.z = f2b(v.z); o.w = f2b(v.w);
  *(u16x4*)(dst + off) = o;
}

// ---------------------------------------------------------------------------
// C[M,N] = A[M,K] @ B[N,K]^T + bias[N]. A,B bf16, bias fp32, fp32 accumulate.
// ---------------------------------------------------------------------------
template <int BM, bool OUT_BF16>
__global__ __launch_bounds__(256) void gemm_bt_bias(
    const uint16_t* __restrict__ A, const uint16_t* __restrict__ B,
    const float* __restrict__ bias, void* __restrict__ Cv,
    int M, int N, int K) {
  constexpr int MI = BM / 32;            // acc rows of 16
  constexpr int CA = BM / 16;            // A chunks per k-half
  constexpr int CPW = (2 * (CA + 8)) / 4;
  constexpr int CT_PITCH = OUT_BF16 ? 72 : 68;
  constexpr size_t CT_BYTES = (size_t)4 * (BM / 2) * CT_PITCH * (OUT_BF16 ? 2 : 4);
  constexpr size_t ST_BYTES = (size_t)(2 * (BM * 32 + 4096)) * 2;
  constexpr size_t LB = CT_BYTES > ST_BYTES ? CT_BYTES : ST_BYTES;
  __shared__ alignas(16) unsigned char ldsb[LB];
  uint16_t* lds = (uint16_t*)ldsb;
  const int offB0 = BM * 32;             // u16 offsets
  const int offA1 = BM * 32 + 4096;
  const int offB1 = 2 * BM * 32 + 4096;

  const int tid = threadIdx.x;
  const int wave = tid >> 6, lane = tid & 63;
  const int q4 = lane >> 4, l16 = lane & 15;
  const int wm = wave >> 1, wn = wave & 1;
  const long blockM = (long)blockIdx.y * BM;
  const long blockN = (long)blockIdx.x * 128;

  f32x4 acc[MI][4] = {};

  for (int k0 = 0; k0 < K; k0 += 64) {
#pragma unroll
    for (int c = 0; c < CPW; ++c) {
      const int id = c * 4 + wave;       // wave-uniform
      const uint16_t* mat; long rowBase; int a, kk, off;
      if (id < CA)               { mat = A; rowBase = blockM; a = id;            kk = k0;      off = 0; }
      else if (id < CA + 8)      { mat = B; rowBase = blockN; a = id - CA;       kk = k0;      off = offB0; }
      else if (id < 2 * CA + 8)  { mat = A; rowBase = blockM; a = id - CA - 8;   kk = k0 + 32; off = offA1; }
      else                       { mat = B; rowBase = blockN; a = id - 2*CA - 8; kk = k0 + 32; off = offB1; }
      const int flat = a * 64 + lane;
      const int row = flat >> 2, seg = flat & 3;
      GLDS16(mat + (rowBase + row) * (long)K + kk + seg * 8, lds + off + a * 512);
    }
    __syncthreads();
#pragma unroll
    for (int h = 0; h < 2; ++h) {
      const uint16_t* Ah = lds + (h ? offA1 : 0);
      const uint16_t* Bh = lds + (h ? offB1 : offB0);
      bf16x8 af[MI], bfr[4];
#pragma unroll
      for (int i = 0; i < MI; ++i)
        af[i] = *(const bf16x8*)&Ah[(wm * (BM / 2) + i * 16 + l16) * 32 + q4 * 8];
#pragma unroll
      for (int j = 0; j < 4; ++j)
        bfr[j] = *(const bf16x8*)&Bh[(wn * 64 + j * 16 + l16) * 32 + q4 * 8];
#pragma unroll
      for (int i = 0; i < MI; ++i)
#pragma unroll
        for (int j = 0; j < 4; ++j)
          acc[i][j] = __builtin_amdgcn_mfma_f32_16x16x32_bf16(af[i], bfr[j], acc[i][j], 0, 0, 0);
    }
    __syncthreads();
  }

  // epilogue: acc (C/D layout: col=l16, row=q4*4+r) -> per-wave LDS tile -> vector stores
  if (OUT_BF16) {
    uint16_t* ct = lds + wave * (BM / 2) * 72;
#pragma unroll
    for (int j = 0; j < 4; ++j) {
      const float bv = bias[blockN + wn * 64 + j * 16 + l16];
#pragma unroll
      for (int i = 0; i < MI; ++i)
#pragma unroll
        for (int r = 0; r < 4; ++r)
          ct[(i * 16 + q4 * 4 + r) * 72 + j * 16 + l16] = f2b(acc[i][j][r] + bv);
    }
    __syncthreads();
    uint16_t* Cb = (uint16_t*)Cv;
#pragma unroll
    for (int st = 0; st < BM / 16; ++st) {
      const int flat = st * 64 + lane;
      const int row = flat >> 3, seg = flat & 7;
      const bf16x8 v = *(const bf16x8*)&ct[row * 72 + seg * 8];
      *(bf16x8*)&Cb[(blockM + wm * (BM / 2) + row) * (long)N + blockN + wn * 64 + seg * 8] = v;
    }
  } else {
    float* ct = (float*)ldsb + wave * (BM / 2) * 68;
#pragma unroll
    for (int j = 0; j < 4; ++j) {
      const float bv = bias[blockN + wn * 64 + j * 16 + l16];
#pragma unroll
      for (int i = 0; i < MI; ++i)
#pragma unroll
        for (int r = 0; r < 4; ++r)
          ct[(i * 16 + q4 * 4 + r) * 68 + j * 16 + l16] = acc[i][j][r] + bv;
    }
    __syncthreads();
    float* Cb = (float*)Cv;
#pragma unroll
    for (int st = 0; st < BM / 8; ++st) {
      const int flat = st * 64 + lane;
      const int row = flat >> 4, seg = flat & 15;
      const f32x4 v = *(const f32x4*)&ct[row * 68 + seg * 4];
      *(f32x4*)&Cb[(blockM + wm * (BM / 2) + row) * (long)N + blockN + wn * 64 + seg * 4] = v;
    }
  }
}

// ---------------------------------------------------------------------------
// Flash-style causal attention, S^T formulation, 32x32x16 MFMA,
// IN-BLOCK split-K with BARRIER-FREE tiles: wave w stages AND consumes only
// its own 32-key slice (KP rows w*32.., its rotated Vt columns) -> no
// __syncthreads in the tile loop (same-wave DS ops complete in order).
// Waves free-run and de-phase, so softmax(VALU) of one wave overlaps
// MFMA/LDS of another — attacks the 48% VALUBusy phase-lock cap seen in
// r1/r7/r9. Barriers only around the per-strip LDS merge.
// Grid: 512 blocks x 256 thr; block p does strips (31-p, p) = 17 tiles.
// bh in LOW bits: XCD serves 4 of 32 heads -> K/V fits private L2.
// NaN guard: pm floored at -3e4 (all-masked tile otherwise sets m_i to the
// ROUNDED -1e30*sc and exp2f(fmaf residual) = inf).
// ---------------------------------------------------------------------------
__global__ __launch_bounds__(256, 2) void attn_flash(
    const uint16_t* __restrict__ kqv, uint16_t* __restrict__ attn) {
  constexpr int T = 2048, C = 1024, C3 = 3072;
  __shared__ alignas(16) unsigned char ldsb[35840];
  uint16_t* KP = (uint16_t*)ldsb;             // [128][72] u16; wave w owns rows w*32..
  uint16_t* Vt = (uint16_t*)(ldsb + 18432);   // [64][136] u16, rot-16 swizzle; per-wave cols
  uint32_t* VtW = (uint32_t*)(ldsb + 18432);  // pitch 68 dwords
  float* mlb  = (float*)ldsb;                 // [4][2][32] (merge overlay)
  float* obuf = (float*)(ldsb + 1024);        // [4][32][66] f32 (merge overlay)

  const int tid = threadIdx.x;
  const int wave = tid >> 6, lane = tid & 63;
  const int l32 = lane & 31, hh = lane >> 5;
  const int pairi = blockIdx.x >> 5, bh = blockIdx.x & 31;
  const int b = bh >> 4, h = bh & 15;
  const size_t base = (size_t)b * T * C3;
  const int hD = h * 64;
  const int lr = lane >> 3, kch = lane & 7;   // per-wave staging coords
  const float sc = 0.125f * 1.4426950408889634f;  // D^-0.5 * log2(e)

  for (int ss = 0; ss < 2; ++ss) {
    const int qb = ss ? pairi : 31 - pairi;   // big strip first
    // per-wave tile count: tiles whose slice key0 = kt*128+wave*32 <= qb*64+63
    const int dd = qb * 64 + 63 - wave * 32;
    const int nktw = (dd < 0) ? 0 : ((dd >> 7) + 1);

    // Q regs: qf[qc][m], B-frag col=l32, k=hh*8+j
    bf16x8 qf[2][4];
#pragma unroll
    for (int qc = 0; qc < 2; ++qc)
#pragma unroll
      for (int m = 0; m < 4; ++m)
        qf[qc][m] = *(const bf16x8*)&kqv[base + (size_t)(qb * 64 + qc * 32 + l32) * C3 + C + hD + m * 16 + hh * 8];

    f32x16 o[2][2] = {};   // [qc][db]: O[q=qc*32+(r&3)+8*(r>>2)+4*hh][d=db*32+l32]
    float m_i[2] = {-1e30f, -1e30f}, l_i[2] = {0.f, 0.f};

    // prefetch own slice of tile 0 into VGPRs
    bf16x8 pk[4], pv0[2], pv1[2];
    if (nktw > 0) {
      const int kb0 = wave * 32;
#pragma unroll
      for (int rr = 0; rr < 4; ++rr)
        pk[rr] = *(const bf16x8*)&kqv[base + (size_t)(kb0 + rr * 8 + lr) * C3 + hD + kch * 8];
#pragma unroll
      for (int s2 = 0; s2 < 2; ++s2) {
        const size_t gg = base + (size_t)(kb0 + 2 * (s2 * 8 + lr)) * C3 + 2 * C + hD + kch * 8;
        pv0[s2] = *(const bf16x8*)&kqv[gg];
        pv1[s2] = *(const bf16x8*)&kqv[gg + C3];
      }
    }

    for (int kt = 0; kt < nktw; ++kt) {
      const int key0 = kt * 128 + wave * 32;
      // stage own K slice (rows wave*32 + rr*8 + lr), b128
#pragma unroll
      for (int rr = 0; rr < 4; ++rr)
        *(bf16x8*)&KP[(wave * 32 + rr * 8 + lr) * 72 + kch * 8] = pk[rr];
      // stage own V slice transposed: pack key-pairs, rot-16 swizzle
#pragma unroll
      for (int s2 = 0; s2 < 2; ++s2) {
        const int colw = (wave * 16 + s2 * 8 + lr + 8 * kch) & 63;
        const uint32_t* a0 = (const uint32_t*)&pv0[s2];
        const uint32_t* a1 = (const uint32_t*)&pv1[s2];
#pragma unroll
        for (int i = 0; i < 8; ++i) {
          const uint32_t w = (i & 1)
              ? __builtin_amdgcn_perm(a1[i >> 1], a0[i >> 1], 0x07060302u)
              : __builtin_amdgcn_perm(a1[i >> 1], a0[i >> 1], 0x05040100u);
          VtW[(kch * 8 + i) * 68 + colw] = w;
        }
      }
      // prefetch own slice of next tile (in flight across compute)
      if (kt + 1 < nktw) {
        const int kb2 = (kt + 1) * 128 + wave * 32;
#pragma unroll
        for (int rr = 0; rr < 4; ++rr)
          pk[rr] = *(const bf16x8*)&kqv[base + (size_t)(kb2 + rr * 8 + lr) * C3 + hD + kch * 8];
#pragma unroll
        for (int s2 = 0; s2 < 2; ++s2) {
          const size_t gg = base + (size_t)(kb2 + 2 * (s2 * 8 + lr)) * C3 + 2 * C + hD + kch * 8;
          pv0[s2] = *(const bf16x8*)&kqv[gg];
          pv1[s2] = *(const bf16x8*)&kqv[gg + C3];
        }
      }

      // kf from own KP rows (same-wave DS in-order: no barrier needed)
      bf16x8 kf[4];
#pragma unroll
      for (int m = 0; m < 4; ++m)
        kf[m] = *(const bf16x8*)&KP[(wave * 32 + l32) * 72 + m * 16 + hh * 8];

#pragma unroll
      for (int qc = 0; qc < 2; ++qc) {
        // skip: slice fully masked for this q-half (wave-uniform)
        if (key0 > qb * 64 + qc * 32 + 31) continue;
        // S^T = K·Q^T : 32 keys x 32 q; lane holds S^T[key(r,hh)][q=l32]
        f32x16 z = {};
#pragma unroll
        for (int m = 0; m < 4; ++m)
          z = __builtin_amdgcn_mfma_f32_32x32x16_bf16(kf[m], qf[qc][m], z, 0, 0, 0);
        if (key0 + 31 > qb * 64 + qc * 32) {   // diagonal band: elementwise mask
          const int qg = qb * 64 + qc * 32 + l32;
#pragma unroll
          for (int r = 0; r < 16; ++r) {
            const int kg = key0 + (r & 3) + 8 * (r >> 2) + 4 * hh;
            if (kg > qg) z[r] = -1e30f;
          }
        }
        // online softmax over this wave's 32 keys (hh-pair exchange only)
        float mloc = -1e30f;
#pragma unroll
        for (int r = 0; r < 16; ++r) mloc = fmaxf(mloc, z[r]);
        mloc = fmaxf(mloc, __shfl_xor(mloc, 32, 64));
        const float pm = fmaxf(mloc * sc, -3.0e4f);   // NaN-guard floor
        if (__any(pm - m_i[qc] > 8.0f)) {   // defer-max
          const float mnew = fmaxf(m_i[qc], pm);
          const float alpha = exp2f(m_i[qc] - mnew);
#pragma unroll
          for (int r = 0; r < 16; ++r) {
            const float ar = __shfl(alpha, (r & 3) + 8 * (r >> 2) + 4 * hh, 64);
            o[qc][0][r] *= ar;
            o[qc][1][r] *= ar;
          }
          l_i[qc] *= alpha;
          m_i[qc] = mnew;
        }
        float rs = 0.f;
#pragma unroll
        for (int r = 0; r < 16; ++r) {
          const float pe = exp2f(fmaf(z[r], sc, -m_i[qc]));
          z[r] = pe;
          rs += pe;
        }
        rs += __shfl_xor(rs, 32, 64);
        l_i[qc] += rs;

        // O += P·V : pack P to bf16, lane-half exchange, 2 k-chunks
        uint32_t x0 = pkbf(z[0], z[1]),   x1 = pkbf(z[2], z[3]);
        uint32_t y0 = pkbf(z[4], z[5]),   y1 = pkbf(z[6], z[7]);
        uint32_t x2 = pkbf(z[8], z[9]),   x3 = pkbf(z[10], z[11]);
        uint32_t y2 = pkbf(z[12], z[13]), y3 = pkbf(z[14], z[15]);
        const uint32_t s0 = hh ? x0 : y0, s1 = hh ? x1 : y1;
        const uint32_t s2 = hh ? x2 : y2, s3 = hh ? x3 : y3;
        const uint32_t t0 = __shfl_xor(s0, 32, 64), t1 = __shfl_xor(s1, 32, 64);
        const uint32_t t2 = __shfl_xor(s2, 32, 64), t3 = __shfl_xor(s3, 32, 64);
#pragma unroll
        for (int cc = 0; cc < 2; ++cc) {
          union { bf16x8 v; uint32_t w[4]; } pa;
          if (cc == 0) {
            pa.w[0] = hh ? t0 : x0; pa.w[1] = hh ? t1 : x1;   // keys 8hh+0..3
            pa.w[2] = hh ? y0 : t0; pa.w[3] = hh ? y1 : t1;   // keys 8hh+4..7
          } else {
            pa.w[0] = hh ? t2 : x2; pa.w[1] = hh ? t3 : x3;
            pa.w[2] = hh ? y2 : t2; pa.w[3] = hh ? y3 : t3;
          }
#pragma unroll
          for (int db = 0; db < 2; ++db) {
            const int d = db * 32 + l32;
            const int col = (wave * 32 + cc * 16 + hh * 8 + 16 * (d >> 3)) & 127;
            const bf16x8 vf = *(const bf16x8*)&Vt[d * 136 + col];
            o[qc][db] = __builtin_amdgcn_mfma_f32_32x32x16_bf16(pa.v, vf, o[qc][db], 0, 0, 0);
          }
        }
      }
    }

    // ---- in-block merge of 4 per-wave partials, one qc-half at a time ----
#pragma unroll
    for (int qc = 0; qc < 2; ++qc) {
      __syncthreads();   // all waves' tiles done (qc=0) / obuf reads done (qc=1)
      if (hh == 0) {
        mlb[wave * 64 + l32] = m_i[qc];
        mlb[wave * 64 + 32 + l32] = l_i[qc];
      }
#pragma unroll
      for (int r = 0; r < 16; ++r) {
        const int ql = (r & 3) + 8 * (r >> 2) + 4 * hh;
        const int bw = wave * 2112 + ql * 66 + l32;
        obuf[bw] = o[qc][0][r];
        obuf[bw + 32] = o[qc][1][r];
      }
      __syncthreads();
      // sum phase: thread = (row q = l32, col-block cb = wave*2+hh)
      float mw[4], lw[4];
#pragma unroll
      for (int w = 0; w < 4; ++w) {
        mw[w] = mlb[w * 64 + l32];
        lw[w] = mlb[w * 64 + 32 + l32];
      }
      const float M = fmaxf(fmaxf(mw[0], mw[1]), fmaxf(mw[2], mw[3]));
      float L = 0.f, ww[4];
#pragma unroll
      for (int w = 0; w < 4; ++w) { ww[w] = exp2f(mw[w] - M); L += lw[w] * ww[w]; }
      const float Li = 1.0f / L;
      const int cb = wave * 2 + hh;
      float acc[8] = {};
#pragma unroll
      for (int w = 0; w < 4; ++w)
#pragma unroll
        for (int p = 0; p < 4; ++p) {
          const float2 v = *(const float2*)&obuf[w * 2112 + l32 * 66 + cb * 8 + p * 2];
          acc[2 * p]     += v.x * ww[w];
          acc[2 * p + 1] += v.y * ww[w];
        }
      union { bf16x8 v; uint32_t w4[4]; } ov;
#pragma unroll
      for (int p = 0; p < 4; ++p)
        ov.w4[p] = pkbf(acc[2 * p] * Li, acc[2 * p + 1] * Li);
      *(bf16x8*)&attn[((size_t)b * T + qb * 64 + qc * 32 + l32) * C + hD + cb * 8] = ov.v;
    }
    __syncthreads();   // merge reads done before next strip overwrites KP/Vt
  }
}

extern "C" void kernel_launch(void* const* d_in, const int* in_sizes, int n_in,
                              void* d_out, int out_size, void* d_ws, size_t ws_size,
                              hipStream_t stream) {
  const float* x      = (const float*)d_in[0];  // (2,2048,1024) fp32
  const float* w_attn = (const float*)d_in[1];  // (3072,1024)  fp32
  const float* b_attn = (const float*)d_in[2];  // (3072,)      fp32
  const float* w_proj = (const float*)d_in[3];  // (1024,1024)  fp32
  const float* b_proj = (const float*)d_in[4];  // (1024,)      fp32
  float* out = (float*)d_out;                   // (2,2048,1024) fp32

  // ws layout (bf16): xb | wab | wpb | kqv | attnb
  uint16_t* xb    = (uint16_t*)d_ws;                     // 4096*1024
  uint16_t* wab   = xb  + (size_t)4096 * 1024;           // 3072*1024
  uint16_t* wpb   = wab + (size_t)3072 * 1024;           // 1024*1024
  uint16_t* kqv   = wpb + (size_t)1024 * 1024;           // 4096*3072
  uint16_t* attnb = kqv + (size_t)4096 * 3072;           // 4096*1024

  dim3 blk(256, 1, 1);
  hipLaunchKernelGGL(cvt_all, dim3(8192), blk, 0, stream, x, w_attn, w_proj, xb, wab, wpb);

  hipLaunchKernelGGL((gemm_bt_bias<128, true>), dim3(3072 / 128, 4096 / 128, 1), blk, 0, stream,
                     xb, wab, b_attn, (void*)kqv, 4096, 3072, 1024);
  hipLaunchKernelGGL(attn_flash, dim3(512, 1, 1), blk, 0, stream, kqv, attnb);
  hipLaunchKernelGGL((gemm_bt_bias<64, false>), dim3(1024 / 128, 4096 / 64, 1), blk, 0, stream,
                     attnb, wpb, b_proj, (void*)out, 4096, 1024, 1024);
}

// Round 11
// 192.420 us; speedup vs baseline: 1.7310x; 1.0031x over previous
//
#include <hip/hip_runtime.h>
#include <hip/hip_bf16.h>
#include <cstdint>

// bf16 fragments as 8 x short (4 VGPRs) per cdna_hip_programming.md §3
typedef __attribute__((ext_vector_type(8))) short bf16x8;
typedef __attribute__((ext_vector_type(4))) float f32x4;
typedef __attribute__((ext_vector_type(16))) float f32x16;
typedef __attribute__((ext_vector_type(4))) uint16_t u16x4;

__device__ __forceinline__ uint16_t f2b(float f) {
  union { float f; uint32_t i; } v; v.f = f;
  return (uint16_t)((v.i + 0x7FFFu + ((v.i >> 16) & 1u)) >> 16);  // RNE
}

__device__ __forceinline__ uint32_t pkbf(float a, float b) {
  union { __hip_bfloat162 h2; uint32_t u; } c;
  c.h2 = __float22bfloat162_rn(make_float2(a, b));
  return c.u;   // low16 = a, high16 = b
}

// async global->LDS, 16B per lane; LDS dest is wave-uniform base + lane*16
#define GLDS16(g, l) __builtin_amdgcn_global_load_lds( \
    (const __attribute__((address_space(1))) void*)(g), \
    (__attribute__((address_space(3))) void*)(l), 16, 0, 0)

// ---------------------------------------------------------------------------
// fp32 -> bf16 convert (RNE) for all three inputs in one launch
// ---------------------------------------------------------------------------
__global__ __launch_bounds__(256) void cvt_all(
    const float* __restrict__ x, const float* __restrict__ wa, const float* __restrict__ wp,
    uint16_t* __restrict__ xb, uint16_t* __restrict__ wab, uint16_t* __restrict__ wpb) {
  const int i = (blockIdx.x * 256 + threadIdx.x) * 4;
  const float* src; uint16_t* dst; int off;
  if (i < 4194304)      { src = x;  dst = xb;  off = i; }
  else if (i < 7340032) { src = wa; dst = wab; off = i - 4194304; }
  else                  { src = wp; dst = wpb; off = i - 7340032; }
  const float4 v = *(const float4*)(src + off);
  u16x4 o;
  o.x = f2b(v.x); o.y = f2b(v.y); o.z = f2b(v.z); o.w = f2b(v.w);
  *(u16x4*)(dst + off) = o;
}

// ---------------------------------------------------------------------------
// C[M,N] = A[M,K] @ B[N,K]^T + bias[N]. A,B bf16, bias fp32, fp32 accumulate.
// ---------------------------------------------------------------------------
template <int BM, bool OUT_BF16>
__global__ __launch_bounds__(256) void gemm_bt_bias(
    const uint16_t* __restrict__ A, const uint16_t* __restrict__ B,
    const float* __restrict__ bias, void* __restrict__ Cv,
    int M, int N, int K) {
  constexpr int MI = BM / 32;            // acc rows of 16
  constexpr int CA = BM / 16;            // A chunks per k-half
  constexpr int CPW = (2 * (CA + 8)) / 4;
  constexpr int CT_PITCH = OUT_BF16 ? 72 : 68;
  constexpr size_t CT_BYTES = (size_t)4 * (BM / 2) * CT_PITCH * (OUT_BF16 ? 2 : 4);
  constexpr size_t ST_BYTES = (size_t)(2 * (BM * 32 + 4096)) * 2;
  constexpr size_t LB = CT_BYTES > ST_BYTES ? CT_BYTES : ST_BYTES;
  __shared__ alignas(16) unsigned char ldsb[LB];
  uint16_t* lds = (uint16_t*)ldsb;
  const int offB0 = BM * 32;             // u16 offsets
  const int offA1 = BM * 32 + 4096;
  const int offB1 = 2 * BM * 32 + 4096;

  const int tid = threadIdx.x;
  const int wave = tid >> 6, lane = tid & 63;
  const int q4 = lane >> 4, l16 = lane & 15;
  const int wm = wave >> 1, wn = wave & 1;
  const long blockM = (long)blockIdx.y * BM;
  const long blockN = (long)blockIdx.x * 128;

  f32x4 acc[MI][4] = {};

  for (int k0 = 0; k0 < K; k0 += 64) {
#pragma unroll
    for (int c = 0; c < CPW; ++c) {
      const int id = c * 4 + wave;       // wave-uniform
      const uint16_t* mat; long rowBase; int a, kk, off;
      if (id < CA)               { mat = A; rowBase = blockM; a = id;            kk = k0;      off = 0; }
      else if (id < CA + 8)      { mat = B; rowBase = blockN; a = id - CA;       kk = k0;      off = offB0; }
      else if (id < 2 * CA + 8)  { mat = A; rowBase = blockM; a = id - CA - 8;   kk = k0 + 32; off = offA1; }
      else                       { mat = B; rowBase = blockN; a = id - 2*CA - 8; kk = k0 + 32; off = offB1; }
      const int flat = a * 64 + lane;
      const int row = flat >> 2, seg = flat & 3;
      GLDS16(mat + (rowBase + row) * (long)K + kk + seg * 8, lds + off + a * 512);
    }
    __syncthreads();
#pragma unroll
    for (int h = 0; h < 2; ++h) {
      const uint16_t* Ah = lds + (h ? offA1 : 0);
      const uint16_t* Bh = lds + (h ? offB1 : offB0);
      bf16x8 af[MI], bfr[4];
#pragma unroll
      for (int i = 0; i < MI; ++i)
        af[i] = *(const bf16x8*)&Ah[(wm * (BM / 2) + i * 16 + l16) * 32 + q4 * 8];
#pragma unroll
      for (int j = 0; j < 4; ++j)
        bfr[j] = *(const bf16x8*)&Bh[(wn * 64 + j * 16 + l16) * 32 + q4 * 8];
#pragma unroll
      for (int i = 0; i < MI; ++i)
#pragma unroll
        for (int j = 0; j < 4; ++j)
          acc[i][j] = __builtin_amdgcn_mfma_f32_16x16x32_bf16(af[i], bfr[j], acc[i][j], 0, 0, 0);
    }
    __syncthreads();
  }

  // epilogue: acc (C/D layout: col=l16, row=q4*4+r) -> per-wave LDS tile -> vector stores
  if (OUT_BF16) {
    uint16_t* ct = lds + wave * (BM / 2) * 72;
#pragma unroll
    for (int j = 0; j < 4; ++j) {
      const float bv = bias[blockN + wn * 64 + j * 16 + l16];
#pragma unroll
      for (int i = 0; i < MI; ++i)
#pragma unroll
        for (int r = 0; r < 4; ++r)
          ct[(i * 16 + q4 * 4 + r) * 72 + j * 16 + l16] = f2b(acc[i][j][r] + bv);
    }
    __syncthreads();
    uint16_t* Cb = (uint16_t*)Cv;
#pragma unroll
    for (int st = 0; st < BM / 16; ++st) {
      const int flat = st * 64 + lane;
      const int row = flat >> 3, seg = flat & 7;
      const bf16x8 v = *(const bf16x8*)&ct[row * 72 + seg * 8];
      *(bf16x8*)&Cb[(blockM + wm * (BM / 2) + row) * (long)N + blockN + wn * 64 + seg * 8] = v;
    }
  } else {
    float* ct = (float*)ldsb + wave * (BM / 2) * 68;
#pragma unroll
    for (int j = 0; j < 4; ++j) {
      const float bv = bias[blockN + wn * 64 + j * 16 + l16];
#pragma unroll
      for (int i = 0; i < MI; ++i)
#pragma unroll
        for (int r = 0; r < 4; ++r)
          ct[(i * 16 + q4 * 4 + r) * 68 + j * 16 + l16] = acc[i][j][r] + bv;
    }
    __syncthreads();
    float* Cb = (float*)Cv;
#pragma unroll
    for (int st = 0; st < BM / 8; ++st) {
      const int flat = st * 64 + lane;
      const int row = flat >> 4, seg = flat & 15;
      const f32x4 v = *(const f32x4*)&ct[row * 68 + seg * 4];
      *(f32x4*)&Cb[(blockM + wm * (BM / 2) + row) * (long)N + blockN + wn * 64 + seg * 4] = v;
    }
  }
}

// ---------------------------------------------------------------------------
// Flash-style causal attention, S^T formulation, 32x32x16 MFMA,
// IN-BLOCK split-K, BARRIER-FREE tiles (r10 verified body) with:
//  * grid 1024 single-strip blocks (qb=31-sidx big-first) -> 4 blocks/CU
//    resident (VGPR ~120 and LDS 35.8KB both allow 4; r10's 512-block grid
//    was the occupancy limiter, not resources)
//  * v_permlane32_swap_b32 for the P lane-half exchange (vdst.hi <-> src.lo;
//    swap(x_,y_): x'={x.lo,y.lo}, y'={x.hi,y.hi}) — provably equal to the
//    verified shfl+select path, removes 12 cndmask + 4 ds_bpermute/qc-tile
//  * tree max/sum reductions (dep depth 15 -> 4)
// bh in LOW bits: XCD serves 4 of 32 heads -> K/V fits private L2.
// NaN guard: pm floored at -3e4 (all-masked tile otherwise sets m_i to the
// ROUNDED -1e30*sc and exp2f(fmaf residual) = inf).
// ---------------------------------------------------------------------------
__global__ __launch_bounds__(256, 2) void attn_flash(
    const uint16_t* __restrict__ kqv, uint16_t* __restrict__ attn) {
  constexpr int T = 2048, C = 1024, C3 = 3072;
  __shared__ alignas(16) unsigned char ldsb[35840];
  uint16_t* KP = (uint16_t*)ldsb;             // [128][72] u16; wave w owns rows w*32..
  uint16_t* Vt = (uint16_t*)(ldsb + 18432);   // [64][136] u16, rot-16 swizzle; per-wave cols
  uint32_t* VtW = (uint32_t*)(ldsb + 18432);  // pitch 68 dwords
  float* mlb  = (float*)ldsb;                 // [4][2][32] (merge overlay)
  float* obuf = (float*)(ldsb + 1024);        // [4][32][66] f32 (merge overlay)

  const int tid = threadIdx.x;
  const int wave = tid >> 6, lane = tid & 63;
  const int l32 = lane & 31, hh = lane >> 5;
  const int sidx = blockIdx.x >> 5, bh = blockIdx.x & 31;
  const int b = bh >> 4, h = bh & 15;
  const size_t base = (size_t)b * T * C3;
  const int hD = h * 64;
  const int lr = lane >> 3, kch = lane & 7;   // per-wave staging coords
  const float sc = 0.125f * 1.4426950408889634f;  // D^-0.5 * log2(e)

  const int qb = 31 - sidx;            // big strips first (backfill order)
  // per-wave tile count: tiles whose slice key0 = kt*128+wave*32 <= qb*64+63
  const int dd = qb * 64 + 63 - wave * 32;
  const int nktw = (dd < 0) ? 0 : ((dd >> 7) + 1);

  // Q regs: qf[qc][m], B-frag col=l32, k=hh*8+j
  bf16x8 qf[2][4];
#pragma unroll
  for (int qc = 0; qc < 2; ++qc)
#pragma unroll
    for (int m = 0; m < 4; ++m)
      qf[qc][m] = *(const bf16x8*)&kqv[base + (size_t)(qb * 64 + qc * 32 + l32) * C3 + C + hD + m * 16 + hh * 8];

  f32x16 o[2][2] = {};   // [qc][db]: O[q=qc*32+(r&3)+8*(r>>2)+4*hh][d=db*32+l32]
  float m_i[2] = {-1e30f, -1e30f}, l_i[2] = {0.f, 0.f};

  // prefetch own slice of tile 0 into VGPRs
  bf16x8 pk[4], pv0[2], pv1[2];
  if (nktw > 0) {
    const int kb0 = wave * 32;
#pragma unroll
    for (int rr = 0; rr < 4; ++rr)
      pk[rr] = *(const bf16x8*)&kqv[base + (size_t)(kb0 + rr * 8 + lr) * C3 + hD + kch * 8];
#pragma unroll
    for (int s2 = 0; s2 < 2; ++s2) {
      const size_t gg = base + (size_t)(kb0 + 2 * (s2 * 8 + lr)) * C3 + 2 * C + hD + kch * 8;
      pv0[s2] = *(const bf16x8*)&kqv[gg];
      pv1[s2] = *(const bf16x8*)&kqv[gg + C3];
    }
  }

  for (int kt = 0; kt < nktw; ++kt) {
    const int key0 = kt * 128 + wave * 32;
    // stage own K slice (rows wave*32 + rr*8 + lr), b128
#pragma unroll
    for (int rr = 0; rr < 4; ++rr)
      *(bf16x8*)&KP[(wave * 32 + rr * 8 + lr) * 72 + kch * 8] = pk[rr];
    // stage own V slice transposed: pack key-pairs, rot-16 swizzle
#pragma unroll
    for (int s2 = 0; s2 < 2; ++s2) {
      const int colw = (wave * 16 + s2 * 8 + lr + 8 * kch) & 63;
      const uint32_t* a0 = (const uint32_t*)&pv0[s2];
      const uint32_t* a1 = (const uint32_t*)&pv1[s2];
#pragma unroll
      for (int i = 0; i < 8; ++i) {
        const uint32_t w = (i & 1)
            ? __builtin_amdgcn_perm(a1[i >> 1], a0[i >> 1], 0x07060302u)
            : __builtin_amdgcn_perm(a1[i >> 1], a0[i >> 1], 0x05040100u);
        VtW[(kch * 8 + i) * 68 + colw] = w;
      }
    }
    // prefetch own slice of next tile (in flight across compute)
    if (kt + 1 < nktw) {
      const int kb2 = (kt + 1) * 128 + wave * 32;
#pragma unroll
      for (int rr = 0; rr < 4; ++rr)
        pk[rr] = *(const bf16x8*)&kqv[base + (size_t)(kb2 + rr * 8 + lr) * C3 + hD + kch * 8];
#pragma unroll
      for (int s2 = 0; s2 < 2; ++s2) {
        const size_t gg = base + (size_t)(kb2 + 2 * (s2 * 8 + lr)) * C3 + 2 * C + hD + kch * 8;
        pv0[s2] = *(const bf16x8*)&kqv[gg];
        pv1[s2] = *(const bf16x8*)&kqv[gg + C3];
      }
    }

    // kf from own KP rows (same-wave DS in-order: no barrier needed)
    bf16x8 kf[4];
#pragma unroll
    for (int m = 0; m < 4; ++m)
      kf[m] = *(const bf16x8*)&KP[(wave * 32 + l32) * 72 + m * 16 + hh * 8];

#pragma unroll
    for (int qc = 0; qc < 2; ++qc) {
      // skip: slice fully masked for this q-half (wave-uniform)
      if (key0 > qb * 64 + qc * 32 + 31) continue;
      // S^T = K·Q^T : 32 keys x 32 q; lane holds S^T[key(r,hh)][q=l32]
      f32x16 z = {};
#pragma unroll
      for (int m = 0; m < 4; ++m)
        z = __builtin_amdgcn_mfma_f32_32x32x16_bf16(kf[m], qf[qc][m], z, 0, 0, 0);
      if (key0 + 31 > qb * 64 + qc * 32) {   // diagonal band: elementwise mask
        const int qg = qb * 64 + qc * 32 + l32;
#pragma unroll
        for (int r = 0; r < 16; ++r) {
          const int kg = key0 + (r & 3) + 8 * (r >> 2) + 4 * hh;
          if (kg > qg) z[r] = -1e30f;
        }
      }
      // online softmax over this wave's 32 keys; tree max (depth 4)
      float t8[8];
#pragma unroll
      for (int r = 0; r < 8; ++r) t8[r] = fmaxf(z[r], z[r + 8]);
#pragma unroll
      for (int r = 0; r < 4; ++r) t8[r] = fmaxf(t8[r], t8[r + 4]);
      float mloc = fmaxf(fmaxf(t8[0], t8[1]), fmaxf(t8[2], t8[3]));
      mloc = fmaxf(mloc, __shfl_xor(mloc, 32, 64));
      const float pm = fmaxf(mloc * sc, -3.0e4f);   // NaN-guard floor
      if (__any(pm - m_i[qc] > 8.0f)) {   // defer-max
        const float mnew = fmaxf(m_i[qc], pm);
        const float alpha = exp2f(m_i[qc] - mnew);
#pragma unroll
        for (int r = 0; r < 16; ++r) {
          const float ar = __shfl(alpha, (r & 3) + 8 * (r >> 2) + 4 * hh, 64);
          o[qc][0][r] *= ar;
          o[qc][1][r] *= ar;
        }
        l_i[qc] *= alpha;
        m_i[qc] = mnew;
      }
#pragma unroll
      for (int r = 0; r < 16; ++r)
        z[r] = exp2f(fmaf(z[r], sc, -m_i[qc]));
      float s8[8];   // tree sum (depth 4)
#pragma unroll
      for (int r = 0; r < 8; ++r) s8[r] = z[r] + z[r + 8];
#pragma unroll
      for (int r = 0; r < 4; ++r) s8[r] += s8[r + 4];
      float rs = (s8[0] + s8[1]) + (s8[2] + s8[3]);
      rs += __shfl_xor(rs, 32, 64);
      l_i[qc] += rs;

      // O += P·V : pack P to bf16; lane-half exchange via permlane32_swap
      // (vdst.hi <-> src.lo): x' = {x.lo, y.lo}, y' = {x.hi, y.hi}
      uint32_t x0 = pkbf(z[0], z[1]),   x1 = pkbf(z[2], z[3]);
      uint32_t y0 = pkbf(z[4], z[5]),   y1 = pkbf(z[6], z[7]);
      uint32_t x2 = pkbf(z[8], z[9]),   x3 = pkbf(z[10], z[11]);
      uint32_t y2 = pkbf(z[12], z[13]), y3 = pkbf(z[14], z[15]);
      asm volatile("v_permlane32_swap_b32 %0, %1" : "+v"(x0), "+v"(y0));
      asm volatile("v_permlane32_swap_b32 %0, %1" : "+v"(x1), "+v"(y1));
      asm volatile("v_permlane32_swap_b32 %0, %1" : "+v"(x2), "+v"(y2));
      asm volatile("v_permlane32_swap_b32 %0, %1" : "+v"(x3), "+v"(y3));
#pragma unroll
      for (int cc = 0; cc < 2; ++cc) {
        union { bf16x8 v; uint32_t w[4]; } pa;
        if (cc == 0) { pa.w[0] = x0; pa.w[1] = x1; pa.w[2] = y0; pa.w[3] = y1; }
        else         { pa.w[0] = x2; pa.w[1] = x3; pa.w[2] = y2; pa.w[3] = y3; }
#pragma unroll
        for (int db = 0; db < 2; ++db) {
          const int d = db * 32 + l32;
          const int col = (wave * 32 + cc * 16 + hh * 8 + 16 * (d >> 3)) & 127;
          const bf16x8 vf = *(const bf16x8*)&Vt[d * 136 + col];
          o[qc][db] = __builtin_amdgcn_mfma_f32_32x32x16_bf16(pa.v, vf, o[qc][db], 0, 0, 0);
        }
      }
    }
  }

  // ---- in-block merge of 4 per-wave partials, one qc-half at a time ----
#pragma unroll
  for (int qc = 0; qc < 2; ++qc) {
    __syncthreads();   // all waves' tiles done (qc=0) / obuf reads done (qc=1)
    if (hh == 0) {
      mlb[wave * 64 + l32] = m_i[qc];
      mlb[wave * 64 + 32 + l32] = l_i[qc];
    }
#pragma unroll
    for (int r = 0; r < 16; ++r) {
      const int ql = (r & 3) + 8 * (r >> 2) + 4 * hh;
      const int bw = wave * 2112 + ql * 66 + l32;
      obuf[bw] = o[qc][0][r];
      obuf[bw + 32] = o[qc][1][r];
    }
    __syncthreads();
    // sum phase: thread = (row q = l32, col-block cb = wave*2+hh)
    float mw[4], lw[4];
#pragma unroll
    for (int w = 0; w < 4; ++w) {
      mw[w] = mlb[w * 64 + l32];
      lw[w] = mlb[w * 64 + 32 + l32];
    }
    const float M = fmaxf(fmaxf(mw[0], mw[1]), fmaxf(mw[2], mw[3]));
    float L = 0.f, ww[4];
#pragma unroll
    for (int w = 0; w < 4; ++w) { ww[w] = exp2f(mw[w] - M); L += lw[w] * ww[w]; }
    const float Li = 1.0f / L;
    const int cb = wave * 2 + hh;
    float acc[8] = {};
#pragma unroll
    for (int w = 0; w < 4; ++w)
#pragma unroll
      for (int p = 0; p < 4; ++p) {
        const float2 v = *(const float2*)&obuf[w * 2112 + l32 * 66 + cb * 8 + p * 2];
        acc[2 * p]     += v.x * ww[w];
        acc[2 * p + 1] += v.y * ww[w];
      }
    union { bf16x8 v; uint32_t w4[4]; } ov;
#pragma unroll
    for (int p = 0; p < 4; ++p)
      ov.w4[p] = pkbf(acc[2 * p] * Li, acc[2 * p + 1] * Li);
    *(bf16x8*)&attn[((size_t)b * T + qb * 64 + qc * 32 + l32) * C + hD + cb * 8] = ov.v;
  }
}

extern "C" void kernel_launch(void* const* d_in, const int* in_sizes, int n_in,
                              void* d_out, int out_size, void* d_ws, size_t ws_size,
                              hipStream_t stream) {
  const float* x      = (const float*)d_in[0];  // (2,2048,1024) fp32
  const float* w_attn = (const float*)d_in[1];  // (3072,1024)  fp32
  const float* b_attn = (const float*)d_in[2];  // (3072,)      fp32
  const float* w_proj = (const float*)d_in[3];  // (1024,1024)  fp32
  const float* b_proj = (const float*)d_in[4];  // (1024,)      fp32
  float* out = (float*)d_out;                   // (2,2048,1024) fp32

  // ws layout (bf16): xb | wab | wpb | kqv | attnb
  uint16_t* xb    = (uint16_t*)d_ws;                     // 4096*1024
  uint16_t* wab   = xb  + (size_t)4096 * 1024;           // 3072*1024
  uint16_t* wpb   = wab + (size_t)3072 * 1024;           // 1024*1024
  uint16_t* kqv   = wpb + (size_t)1024 * 1024;           // 4096*3072
  uint16_t* attnb = kqv + (size_t)4096 * 3072;           // 4096*1024

  dim3 blk(256, 1, 1);
  hipLaunchKernelGGL(cvt_all, dim3(8192), blk, 0, stream, x, w_attn, w_proj, xb, wab, wpb);

  hipLaunchKernelGGL((gemm_bt_bias<128, true>), dim3(3072 / 128, 4096 / 128, 1), blk, 0, stream,
                     xb, wab, b_attn, (void*)kqv, 4096, 3072, 1024);
  hipLaunchKernelGGL(attn_flash, dim3(1024, 1, 1), blk, 0, stream, kqv, attnb);
  hipLaunchKernelGGL((gemm_bt_bias<64, false>), dim3(1024 / 128, 4096 / 64, 1), blk, 0, stream,
                     attnb, wpb, b_proj, (void*)out, 4096, 1024, 1024);
}

// Round 12
// 190.295 us; speedup vs baseline: 1.7503x; 1.0112x over previous
//
#include <hip/hip_runtime.h>
#include <hip/hip_bf16.h>
#include <cstdint>

// bf16 fragments as 8 x short (4 VGPRs) per cdna_hip_programming.md §3
typedef __attribute__((ext_vector_type(8))) short bf16x8;
typedef __attribute__((ext_vector_type(4))) float f32x4;
typedef __attribute__((ext_vector_type(16))) float f32x16;
typedef __attribute__((ext_vector_type(4))) uint16_t u16x4;

__device__ __forceinline__ uint16_t f2b(float f) {
  union { float f; uint32_t i; } v; v.f = f;
  return (uint16_t)((v.i + 0x7FFFu + ((v.i >> 16) & 1u)) >> 16);  // RNE
}

__device__ __forceinline__ uint32_t pkbf(float a, float b) {
  union { __hip_bfloat162 h2; uint32_t u; } c;
  c.h2 = __float22bfloat162_rn(make_float2(a, b));
  return c.u;   // low16 = a, high16 = b
}

// async global->LDS, 16B per lane; LDS dest is wave-uniform base + lane*16
#define GLDS16(g, l) __builtin_amdgcn_global_load_lds( \
    (const __attribute__((address_space(1))) void*)(g), \
    (__attribute__((address_space(3))) void*)(l), 16, 0, 0)

// ---------------------------------------------------------------------------
// fp32 -> bf16 convert (RNE) for all three inputs in one launch
// ---------------------------------------------------------------------------
__global__ __launch_bounds__(256) void cvt_all(
    const float* __restrict__ x, const float* __restrict__ wa, const float* __restrict__ wp,
    uint16_t* __restrict__ xb, uint16_t* __restrict__ wab, uint16_t* __restrict__ wpb) {
  const int i = (blockIdx.x * 256 + threadIdx.x) * 4;
  const float* src; uint16_t* dst; int off;
  if (i < 4194304)      { src = x;  dst = xb;  off = i; }
  else if (i < 7340032) { src = wa; dst = wab; off = i - 4194304; }
  else                  { src = wp; dst = wpb; off = i - 7340032; }
  const float4 v = *(const float4*)(src + off);
  u16x4 o;
  o.x = f2b(v.x); o.y = f2b(v.y); o.z = f2b(v.z); o.w = f2b(v.w);
  *(u16x4*)(dst + off) = o;
}

// ---------------------------------------------------------------------------
// C[M,N] = A[M,K] @ B[N,K]^T + bias[N]. A,B bf16, bias fp32, fp32 accumulate.
// BM x BN block tile, BK=64 (two BK=32 sub-stages per barrier round).
// 4 waves in 2x2: each (BM/2) x (BN/2).
// OUT_BF16: LDS-transposed b128 stores (BN=128 only, as before).
// fp32 out: DIRECT scalar stores (l16 = 16 consecutive cols per quad ->
// 64B-coalesced), no CT buffer -> LDS 24.6KB at BM=128/BN=64, no epilogue
// barriers. This unlocks the 128-row-class K-loop for gemm2 (m92: 64-row
// tile = 343 TF vs 912 for 128-row).
// ---------------------------------------------------------------------------
template <int BM, int BN, bool OUT_BF16>
__global__ __launch_bounds__(256) void gemm_bt_bias(
    const uint16_t* __restrict__ A, const uint16_t* __restrict__ B,
    const float* __restrict__ bias, void* __restrict__ Cv,
    int M, int N, int K) {
  constexpr int MI = BM / 32;            // acc row-tiles per wave
  constexpr int NJ = BN / 32;            // acc col-tiles per wave
  constexpr int CA = BM / 16;            // A chunks per k-half
  constexpr int CB = BN / 16;            // B chunks per k-half
  constexpr int CPW = (2 * (CA + CB)) / 4;
  constexpr size_t CT_BYTES = OUT_BF16 ? (size_t)4 * (BM / 2) * 72 * 2 : 0;
  constexpr size_t ST_BYTES = (size_t)2 * (BM * 32 + BN * 32) * 2;
  constexpr size_t LB = CT_BYTES > ST_BYTES ? CT_BYTES : ST_BYTES;
  __shared__ alignas(16) unsigned char ldsb[LB];
  uint16_t* lds = (uint16_t*)ldsb;
  const int offB0 = BM * 32;             // u16 offsets
  const int offA1 = BM * 32 + BN * 32;
  const int offB1 = 2 * BM * 32 + BN * 32;

  const int tid = threadIdx.x;
  const int wave = tid >> 6, lane = tid & 63;
  const int q4 = lane >> 4, l16 = lane & 15;
  const int wm = wave >> 1, wn = wave & 1;
  const long blockM = (long)blockIdx.y * BM;
  const long blockN = (long)blockIdx.x * BN;

  f32x4 acc[MI][NJ] = {};

  for (int k0 = 0; k0 < K; k0 += 64) {
#pragma unroll
    for (int c = 0; c < CPW; ++c) {
      const int id = c * 4 + wave;       // wave-uniform
      const uint16_t* mat; long rowBase; int a, kk, off;
      if (id < CA)                { mat = A; rowBase = blockM; a = id;             kk = k0;      off = 0; }
      else if (id < CA + CB)      { mat = B; rowBase = blockN; a = id - CA;        kk = k0;      off = offB0; }
      else if (id < 2 * CA + CB)  { mat = A; rowBase = blockM; a = id - CA - CB;   kk = k0 + 32; off = offA1; }
      else                        { mat = B; rowBase = blockN; a = id - 2*CA - CB; kk = k0 + 32; off = offB1; }
      const int flat = a * 64 + lane;
      const int row = flat >> 2, seg = flat & 3;
      GLDS16(mat + (rowBase + row) * (long)K + kk + seg * 8, lds + off + a * 512);
    }
    __syncthreads();
#pragma unroll
    for (int h = 0; h < 2; ++h) {
      const uint16_t* Ah = lds + (h ? offA1 : 0);
      const uint16_t* Bh = lds + (h ? offB1 : offB0);
      bf16x8 af[MI], bfr[NJ];
#pragma unroll
      for (int i = 0; i < MI; ++i)
        af[i] = *(const bf16x8*)&Ah[(wm * (BM / 2) + i * 16 + l16) * 32 + q4 * 8];
#pragma unroll
      for (int j = 0; j < NJ; ++j)
        bfr[j] = *(const bf16x8*)&Bh[(wn * (BN / 2) + j * 16 + l16) * 32 + q4 * 8];
#pragma unroll
      for (int i = 0; i < MI; ++i)
#pragma unroll
        for (int j = 0; j < NJ; ++j)
          acc[i][j] = __builtin_amdgcn_mfma_f32_16x16x32_bf16(af[i], bfr[j], acc[i][j], 0, 0, 0);
    }
    __syncthreads();
  }

  // epilogue: acc (C/D layout: col=l16, row=q4*4+r)
  if constexpr (OUT_BF16) {
    // LDS-transposed vector stores (BN=128 path, unchanged from verified)
    uint16_t* ct = lds + wave * (BM / 2) * 72;
#pragma unroll
    for (int j = 0; j < NJ; ++j) {
      const float bv = bias[blockN + wn * (BN / 2) + j * 16 + l16];
#pragma unroll
      for (int i = 0; i < MI; ++i)
#pragma unroll
        for (int r = 0; r < 4; ++r)
          ct[(i * 16 + q4 * 4 + r) * 72 + j * 16 + l16] = f2b(acc[i][j][r] + bv);
    }
    __syncthreads();
    uint16_t* Cb = (uint16_t*)Cv;
#pragma unroll
    for (int st = 0; st < BM / 16; ++st) {
      const int flat = st * 64 + lane;
      const int row = flat >> 3, seg = flat & 7;
      const bf16x8 v = *(const bf16x8*)&ct[row * 72 + seg * 8];
      *(bf16x8*)&Cb[(blockM + wm * (BM / 2) + row) * (long)N + blockN + wn * 64 + seg * 8] = v;
    }
  } else {
    // direct fp32 stores: quad q4 writes 16 consecutive cols (64B segments)
    float* Cb = (float*)Cv;
#pragma unroll
    for (int j = 0; j < NJ; ++j) {
      const long col = blockN + wn * (BN / 2) + j * 16 + l16;
      const float bv = bias[col];
#pragma unroll
      for (int i = 0; i < MI; ++i)
#pragma unroll
        for (int r = 0; r < 4; ++r) {
          const long row = blockM + wm * (BM / 2) + i * 16 + q4 * 4 + r;
          Cb[row * (long)N + col] = acc[i][j][r] + bv;
        }
    }
  }
}

// ---------------------------------------------------------------------------
// Flash-style causal attention (round-11 verified, unchanged): S^T form,
// 32x32x16 MFMA, in-block split-K, barrier-free tiles, permlane32_swap
// P-exchange, tree reductions, defer-max, -3e4 NaN-guard floor.
// Grid 1024 single-strip blocks, qb=31-sidx big-first, bh in LOW bits.
// ---------------------------------------------------------------------------
__global__ __launch_bounds__(256, 2) void attn_flash(
    const uint16_t* __restrict__ kqv, uint16_t* __restrict__ attn) {
  constexpr int T = 2048, C = 1024, C3 = 3072;
  __shared__ alignas(16) unsigned char ldsb[35840];
  uint16_t* KP = (uint16_t*)ldsb;             // [128][72] u16; wave w owns rows w*32..
  uint16_t* Vt = (uint16_t*)(ldsb + 18432);   // [64][136] u16, rot-16 swizzle; per-wave cols
  uint32_t* VtW = (uint32_t*)(ldsb + 18432);  // pitch 68 dwords
  float* mlb  = (float*)ldsb;                 // [4][2][32] (merge overlay)
  float* obuf = (float*)(ldsb + 1024);        // [4][32][66] f32 (merge overlay)

  const int tid = threadIdx.x;
  const int wave = tid >> 6, lane = tid & 63;
  const int l32 = lane & 31, hh = lane >> 5;
  const int sidx = blockIdx.x >> 5, bh = blockIdx.x & 31;
  const int b = bh >> 4, h = bh & 15;
  const size_t base = (size_t)b * T * C3;
  const int hD = h * 64;
  const int lr = lane >> 3, kch = lane & 7;   // per-wave staging coords
  const float sc = 0.125f * 1.4426950408889634f;  // D^-0.5 * log2(e)

  const int qb = 31 - sidx;            // big strips first (backfill order)
  const int dd = qb * 64 + 63 - wave * 32;
  const int nktw = (dd < 0) ? 0 : ((dd >> 7) + 1);

  // Q regs: qf[qc][m], B-frag col=l32, k=hh*8+j
  bf16x8 qf[2][4];
#pragma unroll
  for (int qc = 0; qc < 2; ++qc)
#pragma unroll
    for (int m = 0; m < 4; ++m)
      qf[qc][m] = *(const bf16x8*)&kqv[base + (size_t)(qb * 64 + qc * 32 + l32) * C3 + C + hD + m * 16 + hh * 8];

  f32x16 o[2][2] = {};   // [qc][db]: O[q=qc*32+(r&3)+8*(r>>2)+4*hh][d=db*32+l32]
  float m_i[2] = {-1e30f, -1e30f}, l_i[2] = {0.f, 0.f};

  // prefetch own slice of tile 0 into VGPRs
  bf16x8 pk[4], pv0[2], pv1[2];
  if (nktw > 0) {
    const int kb0 = wave * 32;
#pragma unroll
    for (int rr = 0; rr < 4; ++rr)
      pk[rr] = *(const bf16x8*)&kqv[base + (size_t)(kb0 + rr * 8 + lr) * C3 + hD + kch * 8];
#pragma unroll
    for (int s2 = 0; s2 < 2; ++s2) {
      const size_t gg = base + (size_t)(kb0 + 2 * (s2 * 8 + lr)) * C3 + 2 * C + hD + kch * 8;
      pv0[s2] = *(const bf16x8*)&kqv[gg];
      pv1[s2] = *(const bf16x8*)&kqv[gg + C3];
    }
  }

  for (int kt = 0; kt < nktw; ++kt) {
    const int key0 = kt * 128 + wave * 32;
    // stage own K slice (rows wave*32 + rr*8 + lr), b128
#pragma unroll
    for (int rr = 0; rr < 4; ++rr)
      *(bf16x8*)&KP[(wave * 32 + rr * 8 + lr) * 72 + kch * 8] = pk[rr];
    // stage own V slice transposed: pack key-pairs, rot-16 swizzle
#pragma unroll
    for (int s2 = 0; s2 < 2; ++s2) {
      const int colw = (wave * 16 + s2 * 8 + lr + 8 * kch) & 63;
      const uint32_t* a0 = (const uint32_t*)&pv0[s2];
      const uint32_t* a1 = (const uint32_t*)&pv1[s2];
#pragma unroll
      for (int i = 0; i < 8; ++i) {
        const uint32_t w = (i & 1)
            ? __builtin_amdgcn_perm(a1[i >> 1], a0[i >> 1], 0x07060302u)
            : __builtin_amdgcn_perm(a1[i >> 1], a0[i >> 1], 0x05040100u);
        VtW[(kch * 8 + i) * 68 + colw] = w;
      }
    }
    // prefetch own slice of next tile (in flight across compute)
    if (kt + 1 < nktw) {
      const int kb2 = (kt + 1) * 128 + wave * 32;
#pragma unroll
      for (int rr = 0; rr < 4; ++rr)
        pk[rr] = *(const bf16x8*)&kqv[base + (size_t)(kb2 + rr * 8 + lr) * C3 + hD + kch * 8];
#pragma unroll
      for (int s2 = 0; s2 < 2; ++s2) {
        const size_t gg = base + (size_t)(kb2 + 2 * (s2 * 8 + lr)) * C3 + 2 * C + hD + kch * 8;
        pv0[s2] = *(const bf16x8*)&kqv[gg];
        pv1[s2] = *(const bf16x8*)&kqv[gg + C3];
      }
    }

    // kf from own KP rows (same-wave DS in-order: no barrier needed)
    bf16x8 kf[4];
#pragma unroll
    for (int m = 0; m < 4; ++m)
      kf[m] = *(const bf16x8*)&KP[(wave * 32 + l32) * 72 + m * 16 + hh * 8];

#pragma unroll
    for (int qc = 0; qc < 2; ++qc) {
      // skip: slice fully masked for this q-half (wave-uniform)
      if (key0 > qb * 64 + qc * 32 + 31) continue;
      // S^T = K·Q^T : 32 keys x 32 q; lane holds S^T[key(r,hh)][q=l32]
      f32x16 z = {};
#pragma unroll
      for (int m = 0; m < 4; ++m)
        z = __builtin_amdgcn_mfma_f32_32x32x16_bf16(kf[m], qf[qc][m], z, 0, 0, 0);
      if (key0 + 31 > qb * 64 + qc * 32) {   // diagonal band: elementwise mask
        const int qg = qb * 64 + qc * 32 + l32;
#pragma unroll
        for (int r = 0; r < 16; ++r) {
          const int kg = key0 + (r & 3) + 8 * (r >> 2) + 4 * hh;
          if (kg > qg) z[r] = -1e30f;
        }
      }
      // online softmax over this wave's 32 keys; tree max (depth 4)
      float t8[8];
#pragma unroll
      for (int r = 0; r < 8; ++r) t8[r] = fmaxf(z[r], z[r + 8]);
#pragma unroll
      for (int r = 0; r < 4; ++r) t8[r] = fmaxf(t8[r], t8[r + 4]);
      float mloc = fmaxf(fmaxf(t8[0], t8[1]), fmaxf(t8[2], t8[3]));
      mloc = fmaxf(mloc, __shfl_xor(mloc, 32, 64));
      const float pm = fmaxf(mloc * sc, -3.0e4f);   // NaN-guard floor
      if (__any(pm - m_i[qc] > 8.0f)) {   // defer-max
        const float mnew = fmaxf(m_i[qc], pm);
        const float alpha = exp2f(m_i[qc] - mnew);
#pragma unroll
        for (int r = 0; r < 16; ++r) {
          const float ar = __shfl(alpha, (r & 3) + 8 * (r >> 2) + 4 * hh, 64);
          o[qc][0][r] *= ar;
          o[qc][1][r] *= ar;
        }
        l_i[qc] *= alpha;
        m_i[qc] = mnew;
      }
#pragma unroll
      for (int r = 0; r < 16; ++r)
        z[r] = exp2f(fmaf(z[r], sc, -m_i[qc]));
      float s8[8];   // tree sum (depth 4)
#pragma unroll
      for (int r = 0; r < 8; ++r) s8[r] = z[r] + z[r + 8];
#pragma unroll
      for (int r = 0; r < 4; ++r) s8[r] += s8[r + 4];
      float rs = (s8[0] + s8[1]) + (s8[2] + s8[3]);
      rs += __shfl_xor(rs, 32, 64);
      l_i[qc] += rs;

      // O += P·V : pack P to bf16; lane-half exchange via permlane32_swap
      // (vdst.hi <-> src.lo): x' = {x.lo, y.lo}, y' = {x.hi, y.hi}
      uint32_t x0 = pkbf(z[0], z[1]),   x1 = pkbf(z[2], z[3]);
      uint32_t y0 = pkbf(z[4], z[5]),   y1 = pkbf(z[6], z[7]);
      uint32_t x2 = pkbf(z[8], z[9]),   x3 = pkbf(z[10], z[11]);
      uint32_t y2 = pkbf(z[12], z[13]), y3 = pkbf(z[14], z[15]);
      asm volatile("v_permlane32_swap_b32 %0, %1" : "+v"(x0), "+v"(y0));
      asm volatile("v_permlane32_swap_b32 %0, %1" : "+v"(x1), "+v"(y1));
      asm volatile("v_permlane32_swap_b32 %0, %1" : "+v"(x2), "+v"(y2));
      asm volatile("v_permlane32_swap_b32 %0, %1" : "+v"(x3), "+v"(y3));
#pragma unroll
      for (int cc = 0; cc < 2; ++cc) {
        union { bf16x8 v; uint32_t w[4]; } pa;
        if (cc == 0) { pa.w[0] = x0; pa.w[1] = x1; pa.w[2] = y0; pa.w[3] = y1; }
        else         { pa.w[0] = x2; pa.w[1] = x3; pa.w[2] = y2; pa.w[3] = y3; }
#pragma unroll
        for (int db = 0; db < 2; ++db) {
          const int d = db * 32 + l32;
          const int col = (wave * 32 + cc * 16 + hh * 8 + 16 * (d >> 3)) & 127;
          const bf16x8 vf = *(const bf16x8*)&Vt[d * 136 + col];
          o[qc][db] = __builtin_amdgcn_mfma_f32_32x32x16_bf16(pa.v, vf, o[qc][db], 0, 0, 0);
        }
      }
    }
  }

  // ---- in-block merge of 4 per-wave partials, one qc-half at a time ----
#pragma unroll
  for (int qc = 0; qc < 2; ++qc) {
    __syncthreads();   // all waves' tiles done (qc=0) / obuf reads done (qc=1)
    if (hh == 0) {
      mlb[wave * 64 + l32] = m_i[qc];
      mlb[wave * 64 + 32 + l32] = l_i[qc];
    }
#pragma unroll
    for (int r = 0; r < 16; ++r) {
      const int ql = (r & 3) + 8 * (r >> 2) + 4 * hh;
      const int bw = wave * 2112 + ql * 66 + l32;
      obuf[bw] = o[qc][0][r];
      obuf[bw + 32] = o[qc][1][r];
    }
    __syncthreads();
    // sum phase: thread = (row q = l32, col-block cb = wave*2+hh)
    float mw[4], lw[4];
#pragma unroll
    for (int w = 0; w < 4; ++w) {
      mw[w] = mlb[w * 64 + l32];
      lw[w] = mlb[w * 64 + 32 + l32];
    }
    const float M = fmaxf(fmaxf(mw[0], mw[1]), fmaxf(mw[2], mw[3]));
    float L = 0.f, ww[4];
#pragma unroll
    for (int w = 0; w < 4; ++w) { ww[w] = exp2f(mw[w] - M); L += lw[w] * ww[w]; }
    const float Li = 1.0f / L;
    const int cb = wave * 2 + hh;
    float acc[8] = {};
#pragma unroll
    for (int w = 0; w < 4; ++w)
#pragma unroll
      for (int p = 0; p < 4; ++p) {
        const float2 v = *(const float2*)&obuf[w * 2112 + l32 * 66 + cb * 8 + p * 2];
        acc[2 * p]     += v.x * ww[w];
        acc[2 * p + 1] += v.y * ww[w];
      }
    union { bf16x8 v; uint32_t w4[4]; } ov;
#pragma unroll
    for (int p = 0; p < 4; ++p)
      ov.w4[p] = pkbf(acc[2 * p] * Li, acc[2 * p + 1] * Li);
    *(bf16x8*)&attn[((size_t)b * T + qb * 64 + qc * 32 + l32) * C + hD + cb * 8] = ov.v;
  }
}

extern "C" void kernel_launch(void* const* d_in, const int* in_sizes, int n_in,
                              void* d_out, int out_size, void* d_ws, size_t ws_size,
                              hipStream_t stream) {
  const float* x      = (const float*)d_in[0];  // (2,2048,1024) fp32
  const float* w_attn = (const float*)d_in[1];  // (3072,1024)  fp32
  const float* b_attn = (const float*)d_in[2];  // (3072,)      fp32
  const float* w_proj = (const float*)d_in[3];  // (1024,1024)  fp32
  const float* b_proj = (const float*)d_in[4];  // (1024,)      fp32
  float* out = (float*)d_out;                   // (2,2048,1024) fp32

  // ws layout (bf16): xb | wab | wpb | kqv | attnb
  uint16_t* xb    = (uint16_t*)d_ws;                     // 4096*1024
  uint16_t* wab   = xb  + (size_t)4096 * 1024;           // 3072*1024
  uint16_t* wpb   = wab + (size_t)3072 * 1024;           // 1024*1024
  uint16_t* kqv   = wpb + (size_t)1024 * 1024;           // 4096*3072
  uint16_t* attnb = kqv + (size_t)4096 * 3072;           // 4096*1024

  dim3 blk(256, 1, 1);
  hipLaunchKernelGGL(cvt_all, dim3(8192), blk, 0, stream, x, w_attn, w_proj, xb, wab, wpb);

  hipLaunchKernelGGL((gemm_bt_bias<128, 128, true>), dim3(3072 / 128, 4096 / 128, 1), blk, 0, stream,
                     xb, wab, b_attn, (void*)kqv, 4096, 3072, 1024);
  hipLaunchKernelGGL(attn_flash, dim3(1024, 1, 1), blk, 0, stream, kqv, attnb);
  hipLaunchKernelGGL((gemm_bt_bias<128, 64, false>), dim3(1024 / 64, 4096 / 128, 1), blk, 0, stream,
                     attnb, wpb, b_proj, (void*)out, 4096, 1024, 1024);
}

// Round 13
// 186.376 us; speedup vs baseline: 1.7871x; 1.0210x over previous
//
#include <hip/hip_runtime.h>
#include <hip/hip_bf16.h>
#include <cstdint>

// bf16 fragments as 8 x short (4 VGPRs) per cdna_hip_programming.md §3
typedef __attribute__((ext_vector_type(8))) short bf16x8;
typedef __attribute__((ext_vector_type(4))) float f32x4;
typedef __attribute__((ext_vector_type(16))) float f32x16;
typedef __attribute__((ext_vector_type(4))) uint16_t u16x4;

__device__ __forceinline__ uint16_t f2b(float f) {
  union { float f; uint32_t i; } v; v.f = f;
  return (uint16_t)((v.i + 0x7FFFu + ((v.i >> 16) & 1u)) >> 16);  // RNE
}

__device__ __forceinline__ uint32_t pkbf(float a, float b) {
  union { __hip_bfloat162 h2; uint32_t u; } c;
  c.h2 = __float22bfloat162_rn(make_float2(a, b));
  return c.u;   // low16 = a, high16 = b
}

// async global->LDS, 16B per lane; LDS dest is wave-uniform base + lane*16
#define GLDS16(g, l) __builtin_amdgcn_global_load_lds( \
    (const __attribute__((address_space(1))) void*)(g), \
    (__attribute__((address_space(3))) void*)(l), 16, 0, 0)

// counted vmcnt wait (literal immediate), with compiler memory fence
#define VMW(n) asm volatile("s_waitcnt vmcnt(" #n ")" ::: "memory")

// ---------------------------------------------------------------------------
// fp32 -> bf16 convert (RNE) for all three inputs in one launch
// ---------------------------------------------------------------------------
__global__ __launch_bounds__(256) void cvt_all(
    const float* __restrict__ x, const float* __restrict__ wa, const float* __restrict__ wp,
    uint16_t* __restrict__ xb, uint16_t* __restrict__ wab, uint16_t* __restrict__ wpb) {
  const int i = (blockIdx.x * 256 + threadIdx.x) * 4;
  const float* src; uint16_t* dst; int off;
  if (i < 4194304)      { src = x;  dst = xb;  off = i; }
  else if (i < 7340032) { src = wa; dst = wab; off = i - 4194304; }
  else                  { src = wp; dst = wpb; off = i - 7340032; }
  const float4 v = *(const float4*)(src + off);
  u16x4 o;
  o.x = f2b(v.x); o.y = f2b(v.y); o.z = f2b(v.z); o.w = f2b(v.w);
  *(u16x4*)(dst + off) = o;
}

// ---------------------------------------------------------------------------
// C[M,N] = A[M,K] @ B[N,K]^T + bias[N]. A,B bf16, bias fp32, fp32 accumulate.
// PIPELINED K-loop (T3+T4): BK=32, 3 LDS buffers, depth-2 prefetch, counted
// vmcnt (never 0 in-loop) via raw s_barrier + asm — the __syncthreads-forced
// vmcnt(0) drain is the m97-structure's ~70% stall (m233); counted vmcnt is
// the isolated +38-73% lever (m218). Race-free by construction:
//   overwrite of buf[(s+2)%3] only after end-barrier following its reads;
//   reads of buf[s%3] only after own vmcnt(2*CPW) + mid-barrier.
// setprio(1) around the MFMA cluster (T5, pays in phase-split schedules).
// Epilogues unchanged: bf16 = LDS-transposed b128 stores; fp32 = direct.
// ---------------------------------------------------------------------------
template <int BM, int BN, bool OUT_BF16>
__global__ __launch_bounds__(256, BN == 128 ? 3 : 4) void gemm_bt_bias(
    const uint16_t* __restrict__ A, const uint16_t* __restrict__ B,
    const float* __restrict__ bias, void* __restrict__ Cv,
    int M, int N, int K) {
  constexpr int MI = BM / 32;            // acc row-tiles per wave
  constexpr int NJ = BN / 32;            // acc col-tiles per wave
  constexpr int CA = BM / 16;            // A chunks per K-step (16 rows x 32K each)
  constexpr int CB = BN / 16;            // B chunks per K-step
  constexpr int CPW = (CA + CB) / 4;     // GLDS16 per thread per K-step (4 or 3)
  constexpr int ABLK = BM * 32;          // u16 per A sub-tile
  constexpr int BUFSZ = (BM + BN) * 32;  // u16 per buffer
  constexpr size_t ST_BYTES = (size_t)3 * BUFSZ * 2;
  constexpr size_t CT_BYTES = OUT_BF16 ? (size_t)4 * (BM / 2) * 72 * 2 : 0;
  constexpr size_t LB = CT_BYTES > ST_BYTES ? CT_BYTES : ST_BYTES;
  __shared__ alignas(16) unsigned char ldsb[LB];
  uint16_t* lds = (uint16_t*)ldsb;

  const int tid = threadIdx.x;
  const int wave = tid >> 6, lane = tid & 63;
  const int q4 = lane >> 4, l16 = lane & 15;
  const int wm = wave >> 1, wn = wave & 1;
  const long blockM = (long)blockIdx.y * BM;
  const long blockN = (long)blockIdx.x * BN;
  const int NK = K >> 5;                 // 32 K-steps of 32

  f32x4 acc[MI][NJ] = {};

  auto STAGE = [&](int s) {
    uint16_t* buf = lds + (s % 3) * BUFSZ;
#pragma unroll
    for (int c = 0; c < CPW; ++c) {
      const int id = c * 4 + wave;       // wave-uniform
      const uint16_t* mat; long rowBase; int a, off;
      if (id < CA) { mat = A; rowBase = blockM; a = id;      off = a * 512; }
      else         { mat = B; rowBase = blockN; a = id - CA; off = ABLK + a * 512; }
      const int flat = a * 64 + lane;
      const int row = flat >> 2, seg = flat & 3;
      GLDS16(mat + (rowBase + row) * (long)K + s * 32 + seg * 8, buf + off);
    }
  };

  STAGE(0);
  STAGE(1);
  for (int s = 0; s < NK; ++s) {
    if (s + 2 < NK) STAGE(s + 2);        // into buf freed by end-barrier of s-1
    __builtin_amdgcn_sched_barrier(0);
    if (s + 2 < NK) {                    // outstanding: stage(s+1), stage(s+2)
      if constexpr (CPW == 4) VMW(8); else VMW(6);
    } else if (s + 2 == NK) {            // outstanding: stage(s+1)
      if constexpr (CPW == 4) VMW(4); else VMW(3);
    } else {
      VMW(0);
    }
    __builtin_amdgcn_sched_barrier(0);
    __builtin_amdgcn_s_barrier();        // everyone's stage(s) landed
    const uint16_t* Ah = lds + (s % 3) * BUFSZ;
    const uint16_t* Bh = Ah + ABLK;
    bf16x8 af[MI], bfr[NJ];
#pragma unroll
    for (int i = 0; i < MI; ++i)
      af[i] = *(const bf16x8*)&Ah[(wm * (BM / 2) + i * 16 + l16) * 32 + q4 * 8];
#pragma unroll
    for (int j = 0; j < NJ; ++j)
      bfr[j] = *(const bf16x8*)&Bh[(wn * (BN / 2) + j * 16 + l16) * 32 + q4 * 8];
    __builtin_amdgcn_s_setprio(1);
#pragma unroll
    for (int i = 0; i < MI; ++i)
#pragma unroll
      for (int j = 0; j < NJ; ++j)
        acc[i][j] = __builtin_amdgcn_mfma_f32_16x16x32_bf16(af[i], bfr[j], acc[i][j], 0, 0, 0);
    __builtin_amdgcn_s_setprio(0);
    __builtin_amdgcn_s_barrier();        // reads of buf[s%3] done -> restageable
  }
  __syncthreads();                       // full drain before LDS reuse / exit

  // epilogue: acc (C/D layout: col=l16, row=q4*4+r)
  if constexpr (OUT_BF16) {
    // LDS-transposed vector stores (BN=128 path, verified)
    uint16_t* ct = lds + wave * (BM / 2) * 72;
#pragma unroll
    for (int j = 0; j < NJ; ++j) {
      const float bv = bias[blockN + wn * (BN / 2) + j * 16 + l16];
#pragma unroll
      for (int i = 0; i < MI; ++i)
#pragma unroll
        for (int r = 0; r < 4; ++r)
          ct[(i * 16 + q4 * 4 + r) * 72 + j * 16 + l16] = f2b(acc[i][j][r] + bv);
    }
    __syncthreads();
    uint16_t* Cb = (uint16_t*)Cv;
#pragma unroll
    for (int st = 0; st < BM / 16; ++st) {
      const int flat = st * 64 + lane;
      const int row = flat >> 3, seg = flat & 7;
      const bf16x8 v = *(const bf16x8*)&ct[row * 72 + seg * 8];
      *(bf16x8*)&Cb[(blockM + wm * (BM / 2) + row) * (long)N + blockN + wn * 64 + seg * 8] = v;
    }
  } else {
    // direct fp32 stores: quad q4 writes 16 consecutive cols (64B segments)
    float* Cb = (float*)Cv;
#pragma unroll
    for (int j = 0; j < NJ; ++j) {
      const long col = blockN + wn * (BN / 2) + j * 16 + l16;
      const float bv = bias[col];
#pragma unroll
      for (int i = 0; i < MI; ++i)
#pragma unroll
        for (int r = 0; r < 4; ++r) {
          const long row = blockM + wm * (BM / 2) + i * 16 + q4 * 4 + r;
          Cb[row * (long)N + col] = acc[i][j][r] + bv;
        }
    }
  }
}

// ---------------------------------------------------------------------------
// Flash-style causal attention (round-11 verified, unchanged): S^T form,
// 32x32x16 MFMA, in-block split-K, barrier-free tiles, permlane32_swap
// P-exchange, tree reductions, defer-max, -3e4 NaN-guard floor.
// Grid 1024 single-strip blocks, qb=31-sidx big-first, bh in LOW bits.
// ---------------------------------------------------------------------------
__global__ __launch_bounds__(256, 2) void attn_flash(
    const uint16_t* __restrict__ kqv, uint16_t* __restrict__ attn) {
  constexpr int T = 2048, C = 1024, C3 = 3072;
  __shared__ alignas(16) unsigned char ldsb[35840];
  uint16_t* KP = (uint16_t*)ldsb;             // [128][72] u16; wave w owns rows w*32..
  uint16_t* Vt = (uint16_t*)(ldsb + 18432);   // [64][136] u16, rot-16 swizzle; per-wave cols
  uint32_t* VtW = (uint32_t*)(ldsb + 18432);  // pitch 68 dwords
  float* mlb  = (float*)ldsb;                 // [4][2][32] (merge overlay)
  float* obuf = (float*)(ldsb + 1024);        // [4][32][66] f32 (merge overlay)

  const int tid = threadIdx.x;
  const int wave = tid >> 6, lane = tid & 63;
  const int l32 = lane & 31, hh = lane >> 5;
  const int sidx = blockIdx.x >> 5, bh = blockIdx.x & 31;
  const int b = bh >> 4, h = bh & 15;
  const size_t base = (size_t)b * T * C3;
  const int hD = h * 64;
  const int lr = lane >> 3, kch = lane & 7;   // per-wave staging coords
  const float sc = 0.125f * 1.4426950408889634f;  // D^-0.5 * log2(e)

  const int qb = 31 - sidx;            // big strips first (backfill order)
  const int dd = qb * 64 + 63 - wave * 32;
  const int nktw = (dd < 0) ? 0 : ((dd >> 7) + 1);

  // Q regs: qf[qc][m], B-frag col=l32, k=hh*8+j
  bf16x8 qf[2][4];
#pragma unroll
  for (int qc = 0; qc < 2; ++qc)
#pragma unroll
    for (int m = 0; m < 4; ++m)
      qf[qc][m] = *(const bf16x8*)&kqv[base + (size_t)(qb * 64 + qc * 32 + l32) * C3 + C + hD + m * 16 + hh * 8];

  f32x16 o[2][2] = {};   // [qc][db]: O[q=qc*32+(r&3)+8*(r>>2)+4*hh][d=db*32+l32]
  float m_i[2] = {-1e30f, -1e30f}, l_i[2] = {0.f, 0.f};

  // prefetch own slice of tile 0 into VGPRs
  bf16x8 pk[4], pv0[2], pv1[2];
  if (nktw > 0) {
    const int kb0 = wave * 32;
#pragma unroll
    for (int rr = 0; rr < 4; ++rr)
      pk[rr] = *(const bf16x8*)&kqv[base + (size_t)(kb0 + rr * 8 + lr) * C3 + hD + kch * 8];
#pragma unroll
    for (int s2 = 0; s2 < 2; ++s2) {
      const size_t gg = base + (size_t)(kb0 + 2 * (s2 * 8 + lr)) * C3 + 2 * C + hD + kch * 8;
      pv0[s2] = *(const bf16x8*)&kqv[gg];
      pv1[s2] = *(const bf16x8*)&kqv[gg + C3];
    }
  }

  for (int kt = 0; kt < nktw; ++kt) {
    const int key0 = kt * 128 + wave * 32;
    // stage own K slice (rows wave*32 + rr*8 + lr), b128
#pragma unroll
    for (int rr = 0; rr < 4; ++rr)
      *(bf16x8*)&KP[(wave * 32 + rr * 8 + lr) * 72 + kch * 8] = pk[rr];
    // stage own V slice transposed: pack key-pairs, rot-16 swizzle
#pragma unroll
    for (int s2 = 0; s2 < 2; ++s2) {
      const int colw = (wave * 16 + s2 * 8 + lr + 8 * kch) & 63;
      const uint32_t* a0 = (const uint32_t*)&pv0[s2];
      const uint32_t* a1 = (const uint32_t*)&pv1[s2];
#pragma unroll
      for (int i = 0; i < 8; ++i) {
        const uint32_t w = (i & 1)
            ? __builtin_amdgcn_perm(a1[i >> 1], a0[i >> 1], 0x07060302u)
            : __builtin_amdgcn_perm(a1[i >> 1], a0[i >> 1], 0x05040100u);
        VtW[(kch * 8 + i) * 68 + colw] = w;
      }
    }
    // prefetch own slice of next tile (in flight across compute)
    if (kt + 1 < nktw) {
      const int kb2 = (kt + 1) * 128 + wave * 32;
#pragma unroll
      for (int rr = 0; rr < 4; ++rr)
        pk[rr] = *(const bf16x8*)&kqv[base + (size_t)(kb2 + rr * 8 + lr) * C3 + hD + kch * 8];
#pragma unroll
      for (int s2 = 0; s2 < 2; ++s2) {
        const size_t gg = base + (size_t)(kb2 + 2 * (s2 * 8 + lr)) * C3 + 2 * C + hD + kch * 8;
        pv0[s2] = *(const bf16x8*)&kqv[gg];
        pv1[s2] = *(const bf16x8*)&kqv[gg + C3];
      }
    }

    // kf from own KP rows (same-wave DS in-order: no barrier needed)
    bf16x8 kf[4];
#pragma unroll
    for (int m = 0; m < 4; ++m)
      kf[m] = *(const bf16x8*)&KP[(wave * 32 + l32) * 72 + m * 16 + hh * 8];

#pragma unroll
    for (int qc = 0; qc < 2; ++qc) {
      // skip: slice fully masked for this q-half (wave-uniform)
      if (key0 > qb * 64 + qc * 32 + 31) continue;
      // S^T = K·Q^T : 32 keys x 32 q; lane holds S^T[key(r,hh)][q=l32]
      f32x16 z = {};
#pragma unroll
      for (int m = 0; m < 4; ++m)
        z = __builtin_amdgcn_mfma_f32_32x32x16_bf16(kf[m], qf[qc][m], z, 0, 0, 0);
      if (key0 + 31 > qb * 64 + qc * 32) {   // diagonal band: elementwise mask
        const int qg = qb * 64 + qc * 32 + l32;
#pragma unroll
        for (int r = 0; r < 16; ++r) {
          const int kg = key0 + (r & 3) + 8 * (r >> 2) + 4 * hh;
          if (kg > qg) z[r] = -1e30f;
        }
      }
      // online softmax over this wave's 32 keys; tree max (depth 4)
      float t8[8];
#pragma unroll
      for (int r = 0; r < 8; ++r) t8[r] = fmaxf(z[r], z[r + 8]);
#pragma unroll
      for (int r = 0; r < 4; ++r) t8[r] = fmaxf(t8[r], t8[r + 4]);
      float mloc = fmaxf(fmaxf(t8[0], t8[1]), fmaxf(t8[2], t8[3]));
      mloc = fmaxf(mloc, __shfl_xor(mloc, 32, 64));
      const float pm = fmaxf(mloc * sc, -3.0e4f);   // NaN-guard floor
      if (__any(pm - m_i[qc] > 8.0f)) {   // defer-max
        const float mnew = fmaxf(m_i[qc], pm);
        const float alpha = exp2f(m_i[qc] - mnew);
#pragma unroll
        for (int r = 0; r < 16; ++r) {
          const float ar = __shfl(alpha, (r & 3) + 8 * (r >> 2) + 4 * hh, 64);
          o[qc][0][r] *= ar;
          o[qc][1][r] *= ar;
        }
        l_i[qc] *= alpha;
        m_i[qc] = mnew;
      }
#pragma unroll
      for (int r = 0; r < 16; ++r)
        z[r] = exp2f(fmaf(z[r], sc, -m_i[qc]));
      float s8[8];   // tree sum (depth 4)
#pragma unroll
      for (int r = 0; r < 8; ++r) s8[r] = z[r] + z[r + 8];
#pragma unroll
      for (int r = 0; r < 4; ++r) s8[r] += s8[r + 4];
      float rs = (s8[0] + s8[1]) + (s8[2] + s8[3]);
      rs += __shfl_xor(rs, 32, 64);
      l_i[qc] += rs;

      // O += P·V : pack P to bf16; lane-half exchange via permlane32_swap
      // (vdst.hi <-> src.lo): x' = {x.lo, y.lo}, y' = {x.hi, y.hi}
      uint32_t x0 = pkbf(z[0], z[1]),   x1 = pkbf(z[2], z[3]);
      uint32_t y0 = pkbf(z[4], z[5]),   y1 = pkbf(z[6], z[7]);
      uint32_t x2 = pkbf(z[8], z[9]),   x3 = pkbf(z[10], z[11]);
      uint32_t y2 = pkbf(z[12], z[13]), y3 = pkbf(z[14], z[15]);
      asm volatile("v_permlane32_swap_b32 %0, %1" : "+v"(x0), "+v"(y0));
      asm volatile("v_permlane32_swap_b32 %0, %1" : "+v"(x1), "+v"(y1));
      asm volatile("v_permlane32_swap_b32 %0, %1" : "+v"(x2), "+v"(y2));
      asm volatile("v_permlane32_swap_b32 %0, %1" : "+v"(x3), "+v"(y3));
#pragma unroll
      for (int cc = 0; cc < 2; ++cc) {
        union { bf16x8 v; uint32_t w[4]; } pa;
        if (cc == 0) { pa.w[0] = x0; pa.w[1] = x1; pa.w[2] = y0; pa.w[3] = y1; }
        else         { pa.w[0] = x2; pa.w[1] = x3; pa.w[2] = y2; pa.w[3] = y3; }
#pragma unroll
        for (int db = 0; db < 2; ++db) {
          const int d = db * 32 + l32;
          const int col = (wave * 32 + cc * 16 + hh * 8 + 16 * (d >> 3)) & 127;
          const bf16x8 vf = *(const bf16x8*)&Vt[d * 136 + col];
          o[qc][db] = __builtin_amdgcn_mfma_f32_32x32x16_bf16(pa.v, vf, o[qc][db], 0, 0, 0);
        }
      }
    }
  }

  // ---- in-block merge of 4 per-wave partials, one qc-half at a time ----
#pragma unroll
  for (int qc = 0; qc < 2; ++qc) {
    __syncthreads();   // all waves' tiles done (qc=0) / obuf reads done (qc=1)
    if (hh == 0) {
      mlb[wave * 64 + l32] = m_i[qc];
      mlb[wave * 64 + 32 + l32] = l_i[qc];
    }
#pragma unroll
    for (int r = 0; r < 16; ++r) {
      const int ql = (r & 3) + 8 * (r >> 2) + 4 * hh;
      const int bw = wave * 2112 + ql * 66 + l32;
      obuf[bw] = o[qc][0][r];
      obuf[bw + 32] = o[qc][1][r];
    }
    __syncthreads();
    // sum phase: thread = (row q = l32, col-block cb = wave*2+hh)
    float mw[4], lw[4];
#pragma unroll
    for (int w = 0; w < 4; ++w) {
      mw[w] = mlb[w * 64 + l32];
      lw[w] = mlb[w * 64 + 32 + l32];
    }
    const float M = fmaxf(fmaxf(mw[0], mw[1]), fmaxf(mw[2], mw[3]));
    float L = 0.f, ww[4];
#pragma unroll
    for (int w = 0; w < 4; ++w) { ww[w] = exp2f(mw[w] - M); L += lw[w] * ww[w]; }
    const float Li = 1.0f / L;
    const int cb = wave * 2 + hh;
    float acc[8] = {};
#pragma unroll
    for (int w = 0; w < 4; ++w)
#pragma unroll
      for (int p = 0; p < 4; ++p) {
        const float2 v = *(const float2*)&obuf[w * 2112 + l32 * 66 + cb * 8 + p * 2];
        acc[2 * p]     += v.x * ww[w];
        acc[2 * p + 1] += v.y * ww[w];
      }
    union { bf16x8 v; uint32_t w4[4]; } ov;
#pragma unroll
    for (int p = 0; p < 4; ++p)
      ov.w4[p] = pkbf(acc[2 * p] * Li, acc[2 * p + 1] * Li);
    *(bf16x8*)&attn[((size_t)b * T + qb * 64 + qc * 32 + l32) * C + hD + cb * 8] = ov.v;
  }
}

extern "C" void kernel_launch(void* const* d_in, const int* in_sizes, int n_in,
                              void* d_out, int out_size, void* d_ws, size_t ws_size,
                              hipStream_t stream) {
  const float* x      = (const float*)d_in[0];  // (2,2048,1024) fp32
  const float* w_attn = (const float*)d_in[1];  // (3072,1024)  fp32
  const float* b_attn = (const float*)d_in[2];  // (3072,)      fp32
  const float* w_proj = (const float*)d_in[3];  // (1024,1024)  fp32
  const float* b_proj = (const float*)d_in[4];  // (1024,)      fp32
  float* out = (float*)d_out;                   // (2,2048,1024) fp32

  // ws layout (bf16): xb | wab | wpb | kqv | attnb
  uint16_t* xb    = (uint16_t*)d_ws;                     // 4096*1024
  uint16_t* wab   = xb  + (size_t)4096 * 1024;           // 3072*1024
  uint16_t* wpb   = wab + (size_t)3072 * 1024;           // 1024*1024
  uint16_t* kqv   = wpb + (size_t)1024 * 1024;           // 4096*3072
  uint16_t* attnb = kqv + (size_t)4096 * 3072;           // 4096*1024

  dim3 blk(256, 1, 1);
  hipLaunchKernelGGL(cvt_all, dim3(8192), blk, 0, stream, x, w_attn, w_proj, xb, wab, wpb);

  hipLaunchKernelGGL((gemm_bt_bias<128, 128, true>), dim3(3072 / 128, 4096 / 128, 1), blk, 0, stream,
                     xb, wab, b_attn, (void*)kqv, 4096, 3072, 1024);
  hipLaunchKernelGGL(attn_flash, dim3(1024, 1, 1), blk, 0, stream, kqv, attnb);
  hipLaunchKernelGGL((gemm_bt_bias<128, 64, false>), dim3(1024 / 64, 4096 / 128, 1), blk, 0, stream,
                     attnb, wpb, b_proj, (void*)out, 4096, 1024, 1024);
}

// Round 14
// 184.396 us; speedup vs baseline: 1.8063x; 1.0107x over previous
//
#include <hip/hip_runtime.h>
#include <hip/hip_bf16.h>
#include <cstdint>

// bf16 fragments as 8 x short (4 VGPRs) per cdna_hip_programming.md §3
typedef __attribute__((ext_vector_type(8))) short bf16x8;
typedef __attribute__((ext_vector_type(4))) float f32x4;
typedef __attribute__((ext_vector_type(16))) float f32x16;
typedef __attribute__((ext_vector_type(4))) uint16_t u16x4;

__device__ __forceinline__ uint16_t f2b(float f) {
  union { float f; uint32_t i; } v; v.f = f;
  return (uint16_t)((v.i + 0x7FFFu + ((v.i >> 16) & 1u)) >> 16);  // RNE
}

__device__ __forceinline__ uint32_t pkbf(float a, float b) {
  union { __hip_bfloat162 h2; uint32_t u; } c;
  c.h2 = __float22bfloat162_rn(make_float2(a, b));
  return c.u;   // low16 = a, high16 = b
}

// async global->LDS, 16B per lane; LDS dest is wave-uniform base + lane*16
#define GLDS16(g, l) __builtin_amdgcn_global_load_lds( \
    (const __attribute__((address_space(1))) void*)(g), \
    (__attribute__((address_space(3))) void*)(l), 16, 0, 0)

// counted vmcnt wait (literal immediate), with compiler memory fence
#define VMW(n) asm volatile("s_waitcnt vmcnt(" #n ")" ::: "memory")

// ---------------------------------------------------------------------------
// fp32 -> bf16 convert (RNE) for all three inputs in one launch
// ---------------------------------------------------------------------------
__global__ __launch_bounds__(256) void cvt_all(
    const float* __restrict__ x, const float* __restrict__ wa, const float* __restrict__ wp,
    uint16_t* __restrict__ xb, uint16_t* __restrict__ wab, uint16_t* __restrict__ wpb) {
  const int i = (blockIdx.x * 256 + threadIdx.x) * 4;
  const float* src; uint16_t* dst; int off;
  if (i < 4194304)      { src = x;  dst = xb;  off = i; }
  else if (i < 7340032) { src = wa; dst = wab; off = i - 4194304; }
  else                  { src = wp; dst = wpb; off = i - 7340032; }
  const float4 v = *(const float4*)(src + off);
  u16x4 o;
  o.x = f2b(v.x); o.y = f2b(v.y); o.z = f2b(v.z); o.w = f2b(v.w);
  *(u16x4*)(dst + off) = o;
}

// ---------------------------------------------------------------------------
// C[M,N] = A[M,K] @ B[N,K]^T + bias[N]. A,B bf16, bias fp32, fp32 accumulate.
// PIPELINED K-loop (T3+T4): BK=32, 3 LDS buffers, depth-2 prefetch, counted
// vmcnt (never 0 in-loop) via raw s_barrier + asm. setprio(1) on MFMA (T5).
// NEW (T2-derived, rule #21): granule XOR swizzle on staging. Fragment reads
// (16 rows x stride 64B at fixed 16B granule) were an 8-way bank conflict
// (bank = 16*row mod 32 -> 2 banks per 16-lane group; m136: 2.94x). Fix:
// lane's 16B granule g = q4 ^ ((row>>1)&3) -> start banks 16(row&1)+4g cover
// all 8 quad-slots exactly twice = 2/bank = HW minimum (free, m136).
// global_load_lds writes linearly, so the permutation is applied to the
// GLOBAL source (seg = (flat&3) ^ ((flat>>3)&3)) and mirrored on the read.
// Epilogues unchanged: bf16 = LDS-transposed b128 stores; fp32 = direct.
// ---------------------------------------------------------------------------
template <int BM, int BN, bool OUT_BF16>
__global__ __launch_bounds__(256, BN == 128 ? 3 : 4) void gemm_bt_bias(
    const uint16_t* __restrict__ A, const uint16_t* __restrict__ B,
    const float* __restrict__ bias, void* __restrict__ Cv,
    int M, int N, int K) {
  constexpr int MI = BM / 32;            // acc row-tiles per wave
  constexpr int NJ = BN / 32;            // acc col-tiles per wave
  constexpr int CA = BM / 16;            // A chunks per K-step (16 rows x 32K each)
  constexpr int CB = BN / 16;            // B chunks per K-step
  constexpr int CPW = (CA + CB) / 4;     // GLDS16 per thread per K-step (4 or 3)
  constexpr int ABLK = BM * 32;          // u16 per A sub-tile
  constexpr int BUFSZ = (BM + BN) * 32;  // u16 per buffer
  constexpr size_t ST_BYTES = (size_t)3 * BUFSZ * 2;
  constexpr size_t CT_BYTES = OUT_BF16 ? (size_t)4 * (BM / 2) * 72 * 2 : 0;
  constexpr size_t LB = CT_BYTES > ST_BYTES ? CT_BYTES : ST_BYTES;
  __shared__ alignas(16) unsigned char ldsb[LB];
  uint16_t* lds = (uint16_t*)ldsb;

  const int tid = threadIdx.x;
  const int wave = tid >> 6, lane = tid & 63;
  const int q4 = lane >> 4, l16 = lane & 15;
  const int wm = wave >> 1, wn = wave & 1;
  const long blockM = (long)blockIdx.y * BM;
  const long blockN = (long)blockIdx.x * BN;
  const int NK = K >> 5;                 // K-steps of 32

  f32x4 acc[MI][NJ] = {};

  auto STAGE = [&](int s) {
    uint16_t* buf = lds + (s % 3) * BUFSZ;
#pragma unroll
    for (int c = 0; c < CPW; ++c) {
      const int id = c * 4 + wave;       // wave-uniform
      const uint16_t* mat; long rowBase; int a, off;
      if (id < CA) { mat = A; rowBase = blockM; a = id;      off = a * 512; }
      else         { mat = B; rowBase = blockN; a = id - CA; off = ABLK + a * 512; }
      const int flat = a * 64 + lane;
      const int row = flat >> 2;
      const int seg = (flat & 3) ^ ((flat >> 3) & 3);   // pre-swizzled source
      GLDS16(mat + (rowBase + row) * (long)K + s * 32 + seg * 8, buf + off);
    }
  };

  STAGE(0);
  STAGE(1);
  for (int s = 0; s < NK; ++s) {
    if (s + 2 < NK) STAGE(s + 2);        // into buf freed by end-barrier of s-1
    __builtin_amdgcn_sched_barrier(0);
    if (s + 2 < NK) {                    // outstanding: stage(s+1), stage(s+2)
      if constexpr (CPW == 4) VMW(8); else VMW(6);
    } else if (s + 2 == NK) {            // outstanding: stage(s+1)
      if constexpr (CPW == 4) VMW(4); else VMW(3);
    } else {
      VMW(0);
    }
    __builtin_amdgcn_sched_barrier(0);
    __builtin_amdgcn_s_barrier();        // everyone's stage(s) landed
    const uint16_t* Ah = lds + (s % 3) * BUFSZ;
    const uint16_t* Bh = Ah + ABLK;
    bf16x8 af[MI], bfr[NJ];
#pragma unroll
    for (int i = 0; i < MI; ++i) {
      const int row = wm * (BM / 2) + i * 16 + l16;
      const int g = q4 ^ ((row >> 1) & 3);             // swizzled granule
      af[i] = *(const bf16x8*)&Ah[row * 32 + g * 8];
    }
#pragma unroll
    for (int j = 0; j < NJ; ++j) {
      const int row = wn * (BN / 2) + j * 16 + l16;
      const int g = q4 ^ ((row >> 1) & 3);
      bfr[j] = *(const bf16x8*)&Bh[row * 32 + g * 8];
    }
    __builtin_amdgcn_s_setprio(1);
#pragma unroll
    for (int i = 0; i < MI; ++i)
#pragma unroll
      for (int j = 0; j < NJ; ++j)
        acc[i][j] = __builtin_amdgcn_mfma_f32_16x16x32_bf16(af[i], bfr[j], acc[i][j], 0, 0, 0);
    __builtin_amdgcn_s_setprio(0);
    __builtin_amdgcn_s_barrier();        // reads of buf[s%3] done -> restageable
  }
  __syncthreads();                       // full drain before LDS reuse / exit

  // epilogue: acc (C/D layout: col=l16, row=q4*4+r)
  if constexpr (OUT_BF16) {
    // LDS-transposed vector stores (BN=128 path, verified)
    uint16_t* ct = lds + wave * (BM / 2) * 72;
#pragma unroll
    for (int j = 0; j < NJ; ++j) {
      const float bv = bias[blockN + wn * (BN / 2) + j * 16 + l16];
#pragma unroll
      for (int i = 0; i < MI; ++i)
#pragma unroll
        for (int r = 0; r < 4; ++r)
          ct[(i * 16 + q4 * 4 + r) * 72 + j * 16 + l16] = f2b(acc[i][j][r] + bv);
    }
    __syncthreads();
    uint16_t* Cb = (uint16_t*)Cv;
#pragma unroll
    for (int st = 0; st < BM / 16; ++st) {
      const int flat = st * 64 + lane;
      const int row = flat >> 3, seg = flat & 7;
      const bf16x8 v = *(const bf16x8*)&ct[row * 72 + seg * 8];
      *(bf16x8*)&Cb[(blockM + wm * (BM / 2) + row) * (long)N + blockN + wn * 64 + seg * 8] = v;
    }
  } else {
    // direct fp32 stores: quad q4 writes 16 consecutive cols (64B segments)
    float* Cb = (float*)Cv;
#pragma unroll
    for (int j = 0; j < NJ; ++j) {
      const long col = blockN + wn * (BN / 2) + j * 16 + l16;
      const float bv = bias[col];
#pragma unroll
      for (int i = 0; i < MI; ++i)
#pragma unroll
        for (int r = 0; r < 4; ++r) {
          const long row = blockM + wm * (BM / 2) + i * 16 + q4 * 4 + r;
          Cb[row * (long)N + col] = acc[i][j][r] + bv;
        }
    }
  }
}

// ---------------------------------------------------------------------------
// Flash-style causal attention (round-11 verified, unchanged): S^T form,
// 32x32x16 MFMA, in-block split-K, barrier-free tiles, permlane32_swap
// P-exchange, tree reductions, defer-max, -3e4 NaN-guard floor.
// Grid 1024 single-strip blocks, qb=31-sidx big-first, bh in LOW bits.
// ---------------------------------------------------------------------------
__global__ __launch_bounds__(256, 2) void attn_flash(
    const uint16_t* __restrict__ kqv, uint16_t* __restrict__ attn) {
  constexpr int T = 2048, C = 1024, C3 = 3072;
  __shared__ alignas(16) unsigned char ldsb[35840];
  uint16_t* KP = (uint16_t*)ldsb;             // [128][72] u16; wave w owns rows w*32..
  uint16_t* Vt = (uint16_t*)(ldsb + 18432);   // [64][136] u16, rot-16 swizzle; per-wave cols
  uint32_t* VtW = (uint32_t*)(ldsb + 18432);  // pitch 68 dwords
  float* mlb  = (float*)ldsb;                 // [4][2][32] (merge overlay)
  float* obuf = (float*)(ldsb + 1024);        // [4][32][66] f32 (merge overlay)

  const int tid = threadIdx.x;
  const int wave = tid >> 6, lane = tid & 63;
  const int l32 = lane & 31, hh = lane >> 5;
  const int sidx = blockIdx.x >> 5, bh = blockIdx.x & 31;
  const int b = bh >> 4, h = bh & 15;
  const size_t base = (size_t)b * T * C3;
  const int hD = h * 64;
  const int lr = lane >> 3, kch = lane & 7;   // per-wave staging coords
  const float sc = 0.125f * 1.4426950408889634f;  // D^-0.5 * log2(e)

  const int qb = 31 - sidx;            // big strips first (backfill order)
  const int dd = qb * 64 + 63 - wave * 32;
  const int nktw = (dd < 0) ? 0 : ((dd >> 7) + 1);

  // Q regs: qf[qc][m], B-frag col=l32, k=hh*8+j
  bf16x8 qf[2][4];
#pragma unroll
  for (int qc = 0; qc < 2; ++qc)
#pragma unroll
    for (int m = 0; m < 4; ++m)
      qf[qc][m] = *(const bf16x8*)&kqv[base + (size_t)(qb * 64 + qc * 32 + l32) * C3 + C + hD + m * 16 + hh * 8];

  f32x16 o[2][2] = {};   // [qc][db]: O[q=qc*32+(r&3)+8*(r>>2)+4*hh][d=db*32+l32]
  float m_i[2] = {-1e30f, -1e30f}, l_i[2] = {0.f, 0.f};

  // prefetch own slice of tile 0 into VGPRs
  bf16x8 pk[4], pv0[2], pv1[2];
  if (nktw > 0) {
    const int kb0 = wave * 32;
#pragma unroll
    for (int rr = 0; rr < 4; ++rr)
      pk[rr] = *(const bf16x8*)&kqv[base + (size_t)(kb0 + rr * 8 + lr) * C3 + hD + kch * 8];
#pragma unroll
    for (int s2 = 0; s2 < 2; ++s2) {
      const size_t gg = base + (size_t)(kb0 + 2 * (s2 * 8 + lr)) * C3 + 2 * C + hD + kch * 8;
      pv0[s2] = *(const bf16x8*)&kqv[gg];
      pv1[s2] = *(const bf16x8*)&kqv[gg + C3];
    }
  }

  for (int kt = 0; kt < nktw; ++kt) {
    const int key0 = kt * 128 + wave * 32;
    // stage own K slice (rows wave*32 + rr*8 + lr), b128
#pragma unroll
    for (int rr = 0; rr < 4; ++rr)
      *(bf16x8*)&KP[(wave * 32 + rr * 8 + lr) * 72 + kch * 8] = pk[rr];
    // stage own V slice transposed: pack key-pairs, rot-16 swizzle
#pragma unroll
    for (int s2 = 0; s2 < 2; ++s2) {
      const int colw = (wave * 16 + s2 * 8 + lr + 8 * kch) & 63;
      const uint32_t* a0 = (const uint32_t*)&pv0[s2];
      const uint32_t* a1 = (const uint32_t*)&pv1[s2];
#pragma unroll
      for (int i = 0; i < 8; ++i) {
        const uint32_t w = (i & 1)
            ? __builtin_amdgcn_perm(a1[i >> 1], a0[i >> 1], 0x07060302u)
            : __builtin_amdgcn_perm(a1[i >> 1], a0[i >> 1], 0x05040100u);
        VtW[(kch * 8 + i) * 68 + colw] = w;
      }
    }
    // prefetch own slice of next tile (in flight across compute)
    if (kt + 1 < nktw) {
      const int kb2 = (kt + 1) * 128 + wave * 32;
#pragma unroll
      for (int rr = 0; rr < 4; ++rr)
        pk[rr] = *(const bf16x8*)&kqv[base + (size_t)(kb2 + rr * 8 + lr) * C3 + hD + kch * 8];
#pragma unroll
      for (int s2 = 0; s2 < 2; ++s2) {
        const size_t gg = base + (size_t)(kb2 + 2 * (s2 * 8 + lr)) * C3 + 2 * C + hD + kch * 8;
        pv0[s2] = *(const bf16x8*)&kqv[gg];
        pv1[s2] = *(const bf16x8*)&kqv[gg + C3];
      }
    }

    // kf from own KP rows (same-wave DS in-order: no barrier needed)
    bf16x8 kf[4];
#pragma unroll
    for (int m = 0; m < 4; ++m)
      kf[m] = *(const bf16x8*)&KP[(wave * 32 + l32) * 72 + m * 16 + hh * 8];

#pragma unroll
    for (int qc = 0; qc < 2; ++qc) {
      // skip: slice fully masked for this q-half (wave-uniform)
      if (key0 > qb * 64 + qc * 32 + 31) continue;
      // S^T = K·Q^T : 32 keys x 32 q; lane holds S^T[key(r,hh)][q=l32]
      f32x16 z = {};
#pragma unroll
      for (int m = 0; m < 4; ++m)
        z = __builtin_amdgcn_mfma_f32_32x32x16_bf16(kf[m], qf[qc][m], z, 0, 0, 0);
      if (key0 + 31 > qb * 64 + qc * 32) {   // diagonal band: elementwise mask
        const int qg = qb * 64 + qc * 32 + l32;
#pragma unroll
        for (int r = 0; r < 16; ++r) {
          const int kg = key0 + (r & 3) + 8 * (r >> 2) + 4 * hh;
          if (kg > qg) z[r] = -1e30f;
        }
      }
      // online softmax over this wave's 32 keys; tree max (depth 4)
      float t8[8];
#pragma unroll
      for (int r = 0; r < 8; ++r) t8[r] = fmaxf(z[r], z[r + 8]);
#pragma unroll
      for (int r = 0; r < 4; ++r) t8[r] = fmaxf(t8[r], t8[r + 4]);
      float mloc = fmaxf(fmaxf(t8[0], t8[1]), fmaxf(t8[2], t8[3]));
      mloc = fmaxf(mloc, __shfl_xor(mloc, 32, 64));
      const float pm = fmaxf(mloc * sc, -3.0e4f);   // NaN-guard floor
      if (__any(pm - m_i[qc] > 8.0f)) {   // defer-max
        const float mnew = fmaxf(m_i[qc], pm);
        const float alpha = exp2f(m_i[qc] - mnew);
#pragma unroll
        for (int r = 0; r < 16; ++r) {
          const float ar = __shfl(alpha, (r & 3) + 8 * (r >> 2) + 4 * hh, 64);
          o[qc][0][r] *= ar;
          o[qc][1][r] *= ar;
        }
        l_i[qc] *= alpha;
        m_i[qc] = mnew;
      }
#pragma unroll
      for (int r = 0; r < 16; ++r)
        z[r] = exp2f(fmaf(z[r], sc, -m_i[qc]));
      float s8[8];   // tree sum (depth 4)
#pragma unroll
      for (int r = 0; r < 8; ++r) s8[r] = z[r] + z[r + 8];
#pragma unroll
      for (int r = 0; r < 4; ++r) s8[r] += s8[r + 4];
      float rs = (s8[0] + s8[1]) + (s8[2] + s8[3]);
      rs += __shfl_xor(rs, 32, 64);
      l_i[qc] += rs;

      // O += P·V : pack P to bf16; lane-half exchange via permlane32_swap
      // (vdst.hi <-> src.lo): x' = {x.lo, y.lo}, y' = {x.hi, y.hi}
      uint32_t x0 = pkbf(z[0], z[1]),   x1 = pkbf(z[2], z[3]);
      uint32_t y0 = pkbf(z[4], z[5]),   y1 = pkbf(z[6], z[7]);
      uint32_t x2 = pkbf(z[8], z[9]),   x3 = pkbf(z[10], z[11]);
      uint32_t y2 = pkbf(z[12], z[13]), y3 = pkbf(z[14], z[15]);
      asm volatile("v_permlane32_swap_b32 %0, %1" : "+v"(x0), "+v"(y0));
      asm volatile("v_permlane32_swap_b32 %0, %1" : "+v"(x1), "+v"(y1));
      asm volatile("v_permlane32_swap_b32 %0, %1" : "+v"(x2), "+v"(y2));
      asm volatile("v_permlane32_swap_b32 %0, %1" : "+v"(x3), "+v"(y3));
#pragma unroll
      for (int cc = 0; cc < 2; ++cc) {
        union { bf16x8 v; uint32_t w[4]; } pa;
        if (cc == 0) { pa.w[0] = x0; pa.w[1] = x1; pa.w[2] = y0; pa.w[3] = y1; }
        else         { pa.w[0] = x2; pa.w[1] = x3; pa.w[2] = y2; pa.w[3] = y3; }
#pragma unroll
        for (int db = 0; db < 2; ++db) {
          const int d = db * 32 + l32;
          const int col = (wave * 32 + cc * 16 + hh * 8 + 16 * (d >> 3)) & 127;
          const bf16x8 vf = *(const bf16x8*)&Vt[d * 136 + col];
          o[qc][db] = __builtin_amdgcn_mfma_f32_32x32x16_bf16(pa.v, vf, o[qc][db], 0, 0, 0);
        }
      }
    }
  }

  // ---- in-block merge of 4 per-wave partials, one qc-half at a time ----
#pragma unroll
  for (int qc = 0; qc < 2; ++qc) {
    __syncthreads();   // all waves' tiles done (qc=0) / obuf reads done (qc=1)
    if (hh == 0) {
      mlb[wave * 64 + l32] = m_i[qc];
      mlb[wave * 64 + 32 + l32] = l_i[qc];
    }
#pragma unroll
    for (int r = 0; r < 16; ++r) {
      const int ql = (r & 3) + 8 * (r >> 2) + 4 * hh;
      const int bw = wave * 2112 + ql * 66 + l32;
      obuf[bw] = o[qc][0][r];
      obuf[bw + 32] = o[qc][1][r];
    }
    __syncthreads();
    // sum phase: thread = (row q = l32, col-block cb = wave*2+hh)
    float mw[4], lw[4];
#pragma unroll
    for (int w = 0; w < 4; ++w) {
      mw[w] = mlb[w * 64 + l32];
      lw[w] = mlb[w * 64 + 32 + l32];
    }
    const float M = fmaxf(fmaxf(mw[0], mw[1]), fmaxf(mw[2], mw[3]));
    float L = 0.f, ww[4];
#pragma unroll
    for (int w = 0; w < 4; ++w) { ww[w] = exp2f(mw[w] - M); L += lw[w] * ww[w]; }
    const float Li = 1.0f / L;
    const int cb = wave * 2 + hh;
    float acc[8] = {};
#pragma unroll
    for (int w = 0; w < 4; ++w)
#pragma unroll
      for (int p = 0; p < 4; ++p) {
        const float2 v = *(const float2*)&obuf[w * 2112 + l32 * 66 + cb * 8 + p * 2];
        acc[2 * p]     += v.x * ww[w];
        acc[2 * p + 1] += v.y * ww[w];
      }
    union { bf16x8 v; uint32_t w4[4]; } ov;
#pragma unroll
    for (int p = 0; p < 4; ++p)
      ov.w4[p] = pkbf(acc[2 * p] * Li, acc[2 * p + 1] * Li);
    *(bf16x8*)&attn[((size_t)b * T + qb * 64 + qc * 32 + l32) * C + hD + cb * 8] = ov.v;
  }
}

extern "C" void kernel_launch(void* const* d_in, const int* in_sizes, int n_in,
                              void* d_out, int out_size, void* d_ws, size_t ws_size,
                              hipStream_t stream) {
  const float* x      = (const float*)d_in[0];  // (2,2048,1024) fp32
  const float* w_attn = (const float*)d_in[1];  // (3072,1024)  fp32
  const float* b_attn = (const float*)d_in[2];  // (3072,)      fp32
  const float* w_proj = (const float*)d_in[3];  // (1024,1024)  fp32
  const float* b_proj = (const float*)d_in[4];  // (1024,)      fp32
  float* out = (float*)d_out;                   // (2,2048,1024) fp32

  // ws layout (bf16): xb | wab | wpb | kqv | attnb
  uint16_t* xb    = (uint16_t*)d_ws;                     // 4096*1024
  uint16_t* wab   = xb  + (size_t)4096 * 1024;           // 3072*1024
  uint16_t* wpb   = wab + (size_t)3072 * 1024;           // 1024*1024
  uint16_t* kqv   = wpb + (size_t)1024 * 1024;           // 4096*3072
  uint16_t* attnb = kqv + (size_t)4096 * 3072;           // 4096*1024

  dim3 blk(256, 1, 1);
  hipLaunchKernelGGL(cvt_all, dim3(8192), blk, 0, stream, x, w_attn, w_proj, xb, wab, wpb);

  hipLaunchKernelGGL((gemm_bt_bias<128, 128, true>), dim3(3072 / 128, 4096 / 128, 1), blk, 0, stream,
                     xb, wab, b_attn, (void*)kqv, 4096, 3072, 1024);
  hipLaunchKernelGGL(attn_flash, dim3(1024, 1, 1), blk, 0, stream, kqv, attnb);
  hipLaunchKernelGGL((gemm_bt_bias<128, 64, false>), dim3(1024 / 64, 4096 / 128, 1), blk, 0, stream,
                     attnb, wpb, b_proj, (void*)out, 4096, 1024, 1024);
}